// Round 1
// baseline (516.403 us; speedup 1.0000x reference)
//
#include <hip/hip_runtime.h>
#include <hip/hip_bf16.h>
#include <math.h>

#define NTOT    50000
#define CDIM    128
#define FCHUNK  2714
#define MCH     18
#define NREM    (NTOT - MCH*FCHUNK)   /* 1148 */
#define NCHUNKS 19
#define TOPKN   5
#define INNERD  512
#define BNEPS   1e-5f

static __device__ __forceinline__ int chunk_n(int chunk) {
    return (chunk < MCH) ? FCHUNK : NREM;
}

// ---------------- K1: W1 = Wv @ Wo  (128x512 @ 512x128) ----------------
__global__ void k1_w1(const float* __restrict__ Wv, const float* __restrict__ Wo,
                      float* __restrict__ W1)
{
    __shared__ float s_wv[INNERD];
    int r = blockIdx.x;
    for (int t = threadIdx.x; t < INNERD; t += blockDim.x) s_wv[t] = Wv[r*INNERD + t];
    __syncthreads();
    int c = threadIdx.x;
    float acc = 0.f;
    #pragma unroll 8
    for (int k = 0; k < INNERD; ++k) acc = fmaf(s_wv[k], Wo[k*CDIM + c], acc);
    W1[r*CDIM + c] = acc;
}

// ---------------- K2: per-chunk top-5 of x_c[j].h_c[i] ----------------
__global__ void k2_topk(const float* __restrict__ x_c, const float* __restrict__ h_c,
                        int* __restrict__ tidx)
{
    __shared__ float4 sx[FCHUNK];
    int chunk = blockIdx.y;
    int base  = chunk * FCHUNK;
    int n     = chunk_n(chunk);
    for (int t = threadIdx.x; t < n; t += blockDim.x) {
        sx[t] = make_float4(x_c[(base+t)*3], x_c[(base+t)*3+1], x_c[(base+t)*3+2], 0.f);
    }
    __syncthreads();
    int il = blockIdx.x * blockDim.x + threadIdx.x;
    if (il >= n) return;
    float h0 = h_c[(base+il)*3], h1 = h_c[(base+il)*3+1], h2 = h_c[(base+il)*3+2];
    float v0=-INFINITY,v1=-INFINITY,v2=-INFINITY,v3=-INFINITY,v4=-INFINITY;
    int   i0=0,i1=0,i2=0,i3=0,i4=0;
    for (int j = 0; j < n; ++j) {
        float4 x = sx[j];
        float s = x.x*h0;            // matches Eigen/XLA k-order: ((x0h0)+x1h1)+x2h2 via fma
        s = fmaf(x.y, h1, s);
        s = fmaf(x.z, h2, s);
        if (s > v4) {                // strict > == lax.top_k stable tie-break
            if (s > v0)      { v4=v3;i4=i3; v3=v2;i3=i2; v2=v1;i2=i1; v1=v0;i1=i0; v0=s;i0=j; }
            else if (s > v1) { v4=v3;i4=i3; v3=v2;i3=i2; v2=v1;i2=i1; v1=s;i1=j; }
            else if (s > v2) { v4=v3;i4=i3; v3=v2;i3=i2; v2=s;i2=j; }
            else if (s > v3) { v4=v3;i4=i3; v3=s;i3=j; }
            else             { v4=s;i4=j; }
        }
    }
    int o = (base+il)*TOPKN;
    tidx[o+0]=i0; tidx[o+1]=i1; tidx[o+2]=i2; tidx[o+3]=i3; tidx[o+4]=i4;
}

// ------- K3: scramble + gather + hsum, then A = hsum @ W1 + bo -------
__global__ void k3_gemm1(const float* __restrict__ x_f, const float* __restrict__ h_f,
                         const int* __restrict__ tidx, const float* __restrict__ W1,
                         const float* __restrict__ bo, float* __restrict__ A)
{
    int chunk = blockIdx.y;
    int base  = chunk * FCHUNK;
    int n     = chunk_n(chunk);
    int row0  = blockIdx.x * 16;
    if (row0 >= n) return;
    int nrows = min(16, n - row0);

    __shared__ int   s_nb[16][TOPKN];
    __shared__ float s_h[16][CDIM];
    __shared__ float s_w[32][CDIM];

    if (threadIdx.x < nrows*TOPKN) {
        int r = threadIdx.x / TOPKN, k = threadIdx.x % TOPKN;
        int il = row0 + r;
        int p  = il*TOPKN + k;                 // faithful tidx.T flatten order
        s_nb[r][k] = tidx[(base + (p % n))*TOPKN + (p / n)];
    }
    __syncthreads();

    for (int e = threadIdx.x; e < nrows*CDIM; e += blockDim.x) {
        int r = e >> 7, c = e & 127;
        int gi = base + row0 + r;
        float s = x_f[gi*CDIM + c];
        #pragma unroll
        for (int k = 0; k < TOPKN; ++k) s += h_f[(base + s_nb[r][k])*CDIM + c];
        s_h[r][c] = s;
    }

    float acc[8] = {0.f,0.f,0.f,0.f,0.f,0.f,0.f,0.f};
    int r  = threadIdx.x >> 4;
    int c0 = (threadIdx.x & 15) << 3;
    for (int kt = 0; kt < CDIM; kt += 32) {
        __syncthreads();
        for (int e = threadIdx.x; e < 32*CDIM; e += blockDim.x)
            s_w[e >> 7][e & 127] = W1[(kt + (e >> 7))*CDIM + (e & 127)];
        __syncthreads();
        if (r < nrows) {
            #pragma unroll
            for (int k = 0; k < 32; ++k) {
                float a = s_h[r][kt + k];
                const float4 w0 = *(const float4*)&s_w[k][c0];
                const float4 w1 = *(const float4*)&s_w[k][c0+4];
                acc[0]=fmaf(a,w0.x,acc[0]); acc[1]=fmaf(a,w0.y,acc[1]);
                acc[2]=fmaf(a,w0.z,acc[2]); acc[3]=fmaf(a,w0.w,acc[3]);
                acc[4]=fmaf(a,w1.x,acc[4]); acc[5]=fmaf(a,w1.y,acc[5]);
                acc[6]=fmaf(a,w1.z,acc[6]); acc[7]=fmaf(a,w1.w,acc[7]);
            }
        }
    }
    if (r < nrows) {
        int gi = base + row0 + r;
        #pragma unroll
        for (int j = 0; j < 8; ++j) A[gi*CDIM + c0 + j] = acc[j] + bo[c0 + j];
    }
}

// ---------------- K4: per-chunk BN stats (sum, sumsq) ----------------
__global__ void k4_cstats(const float* __restrict__ A, float* __restrict__ cstats)
{
    int chunk = blockIdx.y;
    int base  = chunk * FCHUNK;
    int n     = chunk_n(chunk);
    int row0  = blockIdx.x * 128;
    if (row0 >= n) return;
    int nr = min(128, n - row0);
    int c    = threadIdx.x & 127;
    int half = threadIdx.x >> 7;
    float s = 0.f, s2 = 0.f;
    for (int rr = half; rr < nr; rr += 2) {
        float a = A[(base+row0+rr)*CDIM + c];
        s += a; s2 = fmaf(a, a, s2);
    }
    atomicAdd(&cstats[chunk*256 + c], s);
    atomicAdd(&cstats[chunk*256 + 128 + c], s2);
}

// ------- K5: Y = relu(BN_chunk(A)); Z = Y @ Wp + bp  (fused) -------
__global__ void k5_gemm2(const float* __restrict__ A, const float* __restrict__ Wp,
                         const float* __restrict__ bp, const float* __restrict__ gamma_a,
                         const float* __restrict__ beta_a, const float* __restrict__ cstats,
                         float* __restrict__ Z)
{
    int chunk = blockIdx.y;
    int base  = chunk * FCHUNK;
    int n     = chunk_n(chunk);
    int row0  = blockIdx.x * 16;
    if (row0 >= n) return;
    int nrows = min(16, n - row0);

    __shared__ float s_h[16][CDIM];
    __shared__ float s_w[32][CDIM];

    float inv_n = 1.f / (float)n;
    for (int e = threadIdx.x; e < nrows*CDIM; e += blockDim.x) {
        int r = e >> 7, c = e & 127;
        float a   = A[(base+row0+r)*CDIM + c];
        float mu  = cstats[chunk*256 + c] * inv_n;
        float ex2 = cstats[chunk*256 + 128 + c] * inv_n;
        float var = ex2 - mu*mu;
        float y   = gamma_a[c] * (a - mu) * rsqrtf(var + BNEPS) + beta_a[c];
        s_h[r][c] = fmaxf(y, 0.f);
    }

    float acc[8] = {0.f,0.f,0.f,0.f,0.f,0.f,0.f,0.f};
    int r  = threadIdx.x >> 4;
    int c0 = (threadIdx.x & 15) << 3;
    for (int kt = 0; kt < CDIM; kt += 32) {
        __syncthreads();
        for (int e = threadIdx.x; e < 32*CDIM; e += blockDim.x)
            s_w[e >> 7][e & 127] = Wp[(kt + (e >> 7))*CDIM + (e & 127)];
        __syncthreads();
        if (r < nrows) {
            #pragma unroll
            for (int k = 0; k < 32; ++k) {
                float a = s_h[r][kt + k];
                const float4 w0 = *(const float4*)&s_w[k][c0];
                const float4 w1 = *(const float4*)&s_w[k][c0+4];
                acc[0]=fmaf(a,w0.x,acc[0]); acc[1]=fmaf(a,w0.y,acc[1]);
                acc[2]=fmaf(a,w0.z,acc[2]); acc[3]=fmaf(a,w0.w,acc[3]);
                acc[4]=fmaf(a,w1.x,acc[4]); acc[5]=fmaf(a,w1.y,acc[5]);
                acc[6]=fmaf(a,w1.z,acc[6]); acc[7]=fmaf(a,w1.w,acc[7]);
            }
        }
    }
    if (r < nrows) {
        int gi = base + row0 + r;
        #pragma unroll
        for (int j = 0; j < 8; ++j) Z[gi*CDIM + c0 + j] = acc[j] + bp[c0 + j];
    }
}

// ---------------- K6: global BN stats ----------------
__global__ void k6_gstats(const float* __restrict__ Z, float* __restrict__ gstats)
{
    int row0 = blockIdx.x * 128;
    if (row0 >= NTOT) return;
    int nr = min(128, NTOT - row0);
    int c    = threadIdx.x & 127;
    int half = threadIdx.x >> 7;
    float s = 0.f, s2 = 0.f;
    for (int rr = half; rr < nr; rr += 2) {
        float a = Z[(row0+rr)*CDIM + c];
        s += a; s2 = fmaf(a, a, s2);
    }
    atomicAdd(&gstats[c], s);
    atomicAdd(&gstats[128 + c], s2);
}

// ---------------- K7: final BN + ReLU in place ----------------
__global__ void k7_final(float* __restrict__ Z, const float* __restrict__ gstats,
                         const float* __restrict__ gamma_p, const float* __restrict__ beta_p)
{
    int idx = blockIdx.x * blockDim.x + threadIdx.x;
    if (idx >= NTOT*CDIM) return;
    int c = idx & 127;
    const float inv_n = 1.f / (float)NTOT;
    float mu  = gstats[c] * inv_n;
    float var = gstats[128 + c] * inv_n - mu*mu;
    float y   = gamma_p[c] * (Z[idx] - mu) * rsqrtf(var + BNEPS) + beta_p[c];
    Z[idx] = fmaxf(y, 0.f);
}

extern "C" void kernel_launch(void* const* d_in, const int* in_sizes, int n_in,
                              void* d_out, int out_size, void* d_ws, size_t ws_size,
                              hipStream_t stream)
{
    (void)in_sizes; (void)n_in; (void)out_size; (void)ws_size;
    const float* h_f  = (const float*)d_in[0];
    const float* x_f  = (const float*)d_in[1];
    const float* x_c  = (const float*)d_in[2];
    const float* h_c  = (const float*)d_in[3];
    const float* Wv   = (const float*)d_in[6];
    const float* Wo   = (const float*)d_in[7];
    const float* bo   = (const float*)d_in[8];
    const float* ga   = (const float*)d_in[9];
    const float* ba   = (const float*)d_in[10];
    const float* Wp   = (const float*)d_in[11];
    const float* bp   = (const float*)d_in[12];
    const float* gp   = (const float*)d_in[13];
    const float* betp = (const float*)d_in[14];

    char*  ws     = (char*)d_ws;
    float* W1     = (float*)ws;                        // 65536 B
    float* cstats = (float*)(ws + 65536);              // 19*256*4 = 19456 B
    float* gstats = (float*)(ws + 65536 + 19456);      // 1024 B
    int*   tidx   = (int*)(ws + 65536 + 20480);        // 50000*5*4 = 1,000,000 B
    float* A      = (float*)(ws + 65536 + 20480 + 1000000); // 25.6 MB
    float* Z      = (float*)d_out;

    hipMemsetAsync(ws + 65536, 0, 20480, stream);      // zero cstats + gstats

    k1_w1   <<<dim3(CDIM),        dim3(CDIM), 0, stream>>>(Wv, Wo, W1);
    k2_topk <<<dim3(11, NCHUNKS), dim3(256),  0, stream>>>(x_c, h_c, tidx);
    k3_gemm1<<<dim3(170, NCHUNKS),dim3(256),  0, stream>>>(x_f, h_f, tidx, W1, bo, A);
    k4_cstats<<<dim3(22, NCHUNKS),dim3(256),  0, stream>>>(A, cstats);
    k5_gemm2<<<dim3(170, NCHUNKS),dim3(256),  0, stream>>>(A, Wp, bp, ga, ba, cstats, Z);
    k6_gstats<<<dim3(391),        dim3(256),  0, stream>>>(Z, gstats);
    k7_final<<<dim3((NTOT*CDIM + 255)/256), dim3(256), 0, stream>>>(Z, gstats, gp, betp);
}

// Round 3
// 361.781 us; speedup vs baseline: 1.4274x; 1.4274x over previous
//
#include <hip/hip_runtime.h>
#include <hip/hip_bf16.h>
#include <math.h>

#define NTOT    50000
#define CDIM    128
#define FCHUNK  2714
#define MCH     18
#define NREM    (NTOT - MCH*FCHUNK)   /* 1148 */
#define NCHUNKS 19
#define TOPKN   5
#define INNERD  512
#define BNEPS   1e-5f
#define SEGS    8

static __device__ __forceinline__ int chunk_n(int chunk) {
    return (chunk < MCH) ? FCHUNK : NREM;
}

// strict-> sorted insert == lax.top_k stable tie-break
#define INS5(s, jj, V0,V1,V2,V3,V4,I0,I1,I2,I3,I4) \
    if (s > V4) { \
        if (s > V0)      { V4=V3;I4=I3; V3=V2;I3=I2; V2=V1;I2=I1; V1=V0;I1=I0; V0=s;I0=jj; } \
        else if (s > V1) { V4=V3;I4=I3; V3=V2;I3=I2; V2=V1;I2=I1; V1=s;I1=jj; } \
        else if (s > V2) { V4=V3;I4=I3; V3=V2;I3=I2; V2=s;I2=jj; } \
        else if (s > V3) { V4=V3;I4=I3; V3=s;I3=jj; } \
        else             { V4=s;I4=jj; } \
    }

// ---------------- K1: W1 = Wv @ Wo  (128x512 @ 512x128) ----------------
__global__ void k1_w1(const float* __restrict__ Wv, const float* __restrict__ Wo,
                      float* __restrict__ W1)
{
    __shared__ float s_wv[INNERD];
    int r = blockIdx.x;
    for (int t = threadIdx.x; t < INNERD; t += blockDim.x) s_wv[t] = Wv[r*INNERD + t];
    __syncthreads();
    int c = threadIdx.x;
    float acc = 0.f;
    #pragma unroll 8
    for (int k = 0; k < INNERD; ++k) acc = fmaf(s_wv[k], Wo[k*CDIM + c], acc);
    W1[r*CDIM + c] = acc;
}

// ---------------- K2: per-chunk top-5, segment-parallel ----------------
__global__ __launch_bounds__(256) void k2_topk(const float* __restrict__ x_c,
                                               const float* __restrict__ h_c,
                                               int* __restrict__ tidx)
{
    __shared__ float4 sx4[FCHUNK];            // 43424 B; reused for merge
    int chunk = blockIdx.y;
    int base  = chunk * FCHUNK;
    int n     = chunk_n(chunk);
    int row0  = blockIdx.x * 64;
    if (row0 >= n) return;

    for (int t = threadIdx.x; t < n; t += 256)
        sx4[t] = make_float4(x_c[(base+t)*3], x_c[(base+t)*3+1], x_c[(base+t)*3+2], 0.f);
    __syncthreads();

    int seg = threadIdx.x & 7;
    int g   = threadIdx.x >> 3;               // 0..31
    int seglen = ((n + SEGS - 1) / SEGS) | 1; // odd -> distinct LDS banks per seg
    int j0 = seg*seglen, j1 = min(n, j0 + seglen);

    int rA = row0 + g, rB = row0 + g + 32;
    bool vA = rA < n, vB = rB < n;
    float hA0=0,hA1=0,hA2=0,hB0=0,hB1=0,hB2=0;
    if (vA){ hA0=h_c[(base+rA)*3]; hA1=h_c[(base+rA)*3+1]; hA2=h_c[(base+rA)*3+2]; }
    if (vB){ hB0=h_c[(base+rB)*3]; hB1=h_c[(base+rB)*3+1]; hB2=h_c[(base+rB)*3+2]; }

    float aV0=-INFINITY,aV1=-INFINITY,aV2=-INFINITY,aV3=-INFINITY,aV4=-INFINITY;
    float bV0=-INFINITY,bV1=-INFINITY,bV2=-INFINITY,bV3=-INFINITY,bV4=-INFINITY;
    int aI0=0,aI1=0,aI2=0,aI3=0,aI4=0, bI0=0,bI1=0,bI2=0,bI3=0,bI4=0;

    for (int j = j0; j < j1; ++j) {
        float4 x = sx4[j];
        float sA = fmaf(x.z,hA2, fmaf(x.y,hA1, x.x*hA0)); // same fma order as XLA path
        float sB = fmaf(x.z,hB2, fmaf(x.y,hB1, x.x*hB0));
        INS5(sA, j, aV0,aV1,aV2,aV3,aV4, aI0,aI1,aI2,aI3,aI4);
        INS5(sB, j, bV0,bV1,bV2,bV3,bV4, bI0,bI1,bI2,bI3,bI4);
    }
    __syncthreads();

    float* cv = (float*)sx4;                  // [64][8][5] values
    int*   ci = (int*)(cv + 64*40);           // [64][8][5] indices
    int offA = (g*8 + seg)*5;
    int offB = ((g+32)*8 + seg)*5;
    cv[offA+0]=aV0; cv[offA+1]=aV1; cv[offA+2]=aV2; cv[offA+3]=aV3; cv[offA+4]=aV4;
    ci[offA+0]=aI0; ci[offA+1]=aI1; ci[offA+2]=aI2; ci[offA+3]=aI3; ci[offA+4]=aI4;
    cv[offB+0]=bV0; cv[offB+1]=bV1; cv[offB+2]=bV2; cv[offB+3]=bV3; cv[offB+4]=bV4;
    ci[offB+0]=bI0; ci[offB+1]=bI1; ci[offB+2]=bI2; ci[offB+3]=bI3; ci[offB+4]=bI4;
    __syncthreads();

    if (threadIdx.x < 64) {
        int lr = threadIdx.x, row = row0 + lr;
        if (row < n) {
            float v0=-INFINITY,v1=-INFINITY,v2=-INFINITY,v3=-INFINITY,v4=-INFINITY;
            int i0=0,i1=0,i2=0,i3=0,i4=0;
            for (int t = 0; t < 40; ++t) {    // segment order == ascending j -> stable ties
                float s = cv[lr*40 + t]; int jj = ci[lr*40 + t];
                INS5(s, jj, v0,v1,v2,v3,v4, i0,i1,i2,i3,i4);
            }
            int o = (base+row)*TOPKN;
            tidx[o+0]=i0; tidx[o+1]=i1; tidx[o+2]=i2; tidx[o+3]=i3; tidx[o+4]=i4;
        }
    }
}

// ------- K3: scramble + gather + hsum, then A = hsum @ W1 + bo -------
__global__ __launch_bounds__(256) void k3_gemm1(const float* __restrict__ x_f,
                         const float* __restrict__ h_f,
                         const int* __restrict__ tidx, const float* __restrict__ W1,
                         const float* __restrict__ bo, float* __restrict__ A)
{
    __shared__ float s_h[64][132];
    __shared__ float s_w[32][128];
    __shared__ int   s_nb[64][TOPKN];
    int chunk = blockIdx.y;
    int base  = chunk * FCHUNK;
    int n     = chunk_n(chunk);
    int row0  = blockIdx.x * 64;
    if (row0 >= n) return;

    for (int e = threadIdx.x; e < 64*TOPKN; e += 256) {   // FIX: 320 entries, 256 threads
        int r = e / TOPKN, k = e % TOPKN;
        int il = row0 + r;
        int nb = 0;
        if (il < n) {
            int p = il*TOPKN + k;             // faithful tidx.T flatten order
            int q, m;
            if (n == FCHUNK) { q = p / FCHUNK; m = p - q*FCHUNK; }
            else             { q = p / NREM;   m = p - q*NREM; }
            nb = tidx[(base + m)*TOPKN + q];
        }
        s_nb[r][k] = nb;
    }
    __syncthreads();

    for (int e = threadIdx.x; e < 64*32; e += 256) {
        int r = e >> 5, c4 = e & 31;
        float4 acc4 = make_float4(0.f,0.f,0.f,0.f);
        int gr = row0 + r;
        if (gr < n) {
            acc4 = *(const float4*)&x_f[(base+gr)*CDIM + c4*4];
            #pragma unroll
            for (int k = 0; k < TOPKN; ++k) {
                float4 h4 = *(const float4*)&h_f[(base + s_nb[r][k])*CDIM + c4*4];
                acc4.x += h4.x; acc4.y += h4.y; acc4.z += h4.z; acc4.w += h4.w;
            }
        }
        *(float4*)&s_h[r][c4*4] = acc4;
    }

    float acc[4][8];
    #pragma unroll
    for (int i = 0; i < 4; ++i)
        #pragma unroll
        for (int j = 0; j < 8; ++j) acc[i][j] = 0.f;
    int tx = threadIdx.x & 15, ty = threadIdx.x >> 4;
    int c0 = tx*8, r0 = ty*4;

    for (int kt = 0; kt < CDIM; kt += 32) {
        __syncthreads();
        for (int e = threadIdx.x; e < 32*32; e += 256) {
            int kr = e >> 5, c4 = e & 31;
            *(float4*)&s_w[kr][c4*4] = *(const float4*)&W1[(kt+kr)*CDIM + c4*4];
        }
        __syncthreads();
        #pragma unroll
        for (int kk = 0; kk < 32; kk += 4) {
            float a[4][4];
            #pragma unroll
            for (int ri = 0; ri < 4; ++ri)
                *(float4*)a[ri] = *(const float4*)&s_h[r0+ri][kt+kk];
            #pragma unroll
            for (int dk = 0; dk < 4; ++dk) {
                float4 w0 = *(const float4*)&s_w[kk+dk][c0];
                float4 w1 = *(const float4*)&s_w[kk+dk][c0+4];
                #pragma unroll
                for (int ri = 0; ri < 4; ++ri) {
                    float av = a[ri][dk];
                    acc[ri][0]=fmaf(av,w0.x,acc[ri][0]); acc[ri][1]=fmaf(av,w0.y,acc[ri][1]);
                    acc[ri][2]=fmaf(av,w0.z,acc[ri][2]); acc[ri][3]=fmaf(av,w0.w,acc[ri][3]);
                    acc[ri][4]=fmaf(av,w1.x,acc[ri][4]); acc[ri][5]=fmaf(av,w1.y,acc[ri][5]);
                    acc[ri][6]=fmaf(av,w1.z,acc[ri][6]); acc[ri][7]=fmaf(av,w1.w,acc[ri][7]);
                }
            }
        }
    }

    #pragma unroll
    for (int ri = 0; ri < 4; ++ri) {
        int gr = row0 + r0 + ri;
        if (gr < n) {
            float* out = &A[(base+gr)*CDIM + c0];
            #pragma unroll
            for (int j = 0; j < 8; ++j) out[j] = acc[ri][j] + bo[c0 + j];
        }
    }
}

// ---------------- K4: per-chunk BN stats (sum, sumsq) ----------------
__global__ void k4_cstats(const float* __restrict__ A, float* __restrict__ cstats)
{
    int chunk = blockIdx.y;
    int base  = chunk * FCHUNK;
    int n     = chunk_n(chunk);
    int row0  = blockIdx.x * 128;
    if (row0 >= n) return;
    int nr = min(128, n - row0);
    int c    = threadIdx.x & 127;
    int half = threadIdx.x >> 7;
    float s = 0.f, s2 = 0.f;
    for (int rr = half; rr < nr; rr += 2) {
        float a = A[(base+row0+rr)*CDIM + c];
        s += a; s2 = fmaf(a, a, s2);
    }
    atomicAdd(&cstats[chunk*256 + c], s);
    atomicAdd(&cstats[chunk*256 + 128 + c], s2);
}

// ------- K5: Y = relu(BN_chunk(A)); Z = Y @ Wp + bp  (fused) -------
__global__ __launch_bounds__(256) void k5_gemm2(const float* __restrict__ A,
                         const float* __restrict__ Wp,
                         const float* __restrict__ bp, const float* __restrict__ gamma_a,
                         const float* __restrict__ beta_a, const float* __restrict__ cstats,
                         float* __restrict__ Z)
{
    __shared__ float s_h[64][132];
    __shared__ float s_w[32][128];
    __shared__ float s_sc[CDIM], s_sf[CDIM];
    int chunk = blockIdx.y;
    int base  = chunk * FCHUNK;
    int n     = chunk_n(chunk);
    int row0  = blockIdx.x * 64;
    if (row0 >= n) return;

    if (threadIdx.x < CDIM) {
        int c = threadIdx.x;
        float inv_n = 1.f / (float)n;
        float mu  = cstats[chunk*256 + c] * inv_n;
        float var = cstats[chunk*256 + 128 + c] * inv_n - mu*mu;
        float sc  = gamma_a[c] * rsqrtf(var + BNEPS);
        s_sc[c] = sc;
        s_sf[c] = beta_a[c] - mu*sc;
    }
    __syncthreads();

    for (int e = threadIdx.x; e < 64*32; e += 256) {
        int r = e >> 5, c4 = e & 31;
        float4 y = make_float4(0.f,0.f,0.f,0.f);
        int gr = row0 + r;
        if (gr < n) {
            float4 a4 = *(const float4*)&A[(base+gr)*CDIM + c4*4];
            int c = c4*4;
            y.x = fmaxf(fmaf(a4.x, s_sc[c+0], s_sf[c+0]), 0.f);
            y.y = fmaxf(fmaf(a4.y, s_sc[c+1], s_sf[c+1]), 0.f);
            y.z = fmaxf(fmaf(a4.z, s_sc[c+2], s_sf[c+2]), 0.f);
            y.w = fmaxf(fmaf(a4.w, s_sc[c+3], s_sf[c+3]), 0.f);
        }
        *(float4*)&s_h[r][c4*4] = y;
    }

    float acc[4][8];
    #pragma unroll
    for (int i = 0; i < 4; ++i)
        #pragma unroll
        for (int j = 0; j < 8; ++j) acc[i][j] = 0.f;
    int tx = threadIdx.x & 15, ty = threadIdx.x >> 4;
    int c0 = tx*8, r0 = ty*4;

    for (int kt = 0; kt < CDIM; kt += 32) {
        __syncthreads();
        for (int e = threadIdx.x; e < 32*32; e += 256) {
            int kr = e >> 5, c4 = e & 31;
            *(float4*)&s_w[kr][c4*4] = *(const float4*)&Wp[(kt+kr)*CDIM + c4*4];
        }
        __syncthreads();
        #pragma unroll
        for (int kk = 0; kk < 32; kk += 4) {
            float a[4][4];
            #pragma unroll
            for (int ri = 0; ri < 4; ++ri)
                *(float4*)a[ri] = *(const float4*)&s_h[r0+ri][kt+kk];
            #pragma unroll
            for (int dk = 0; dk < 4; ++dk) {
                float4 w0 = *(const float4*)&s_w[kk+dk][c0];
                float4 w1 = *(const float4*)&s_w[kk+dk][c0+4];
                #pragma unroll
                for (int ri = 0; ri < 4; ++ri) {
                    float av = a[ri][dk];
                    acc[ri][0]=fmaf(av,w0.x,acc[ri][0]); acc[ri][1]=fmaf(av,w0.y,acc[ri][1]);
                    acc[ri][2]=fmaf(av,w0.z,acc[ri][2]); acc[ri][3]=fmaf(av,w0.w,acc[ri][3]);
                    acc[ri][4]=fmaf(av,w1.x,acc[ri][4]); acc[ri][5]=fmaf(av,w1.y,acc[ri][5]);
                    acc[ri][6]=fmaf(av,w1.z,acc[ri][6]); acc[ri][7]=fmaf(av,w1.w,acc[ri][7]);
                }
            }
        }
    }

    #pragma unroll
    for (int ri = 0; ri < 4; ++ri) {
        int gr = row0 + r0 + ri;
        if (gr < n) {
            float* out = &Z[(base+gr)*CDIM + c0];
            #pragma unroll
            for (int j = 0; j < 8; ++j) out[j] = acc[ri][j] + bp[c0 + j];
        }
    }
}

// ---------------- K6: global BN stats ----------------
__global__ void k6_gstats(const float* __restrict__ Z, float* __restrict__ gstats)
{
    int row0 = blockIdx.x * 128;
    if (row0 >= NTOT) return;
    int nr = min(128, NTOT - row0);
    int c    = threadIdx.x & 127;
    int half = threadIdx.x >> 7;
    float s = 0.f, s2 = 0.f;
    for (int rr = half; rr < nr; rr += 2) {
        float a = Z[(row0+rr)*CDIM + c];
        s += a; s2 = fmaf(a, a, s2);
    }
    atomicAdd(&gstats[c], s);
    atomicAdd(&gstats[128 + c], s2);
}

// ---------------- K7: final BN + ReLU in place (float4) ----------------
__global__ void k7_final(float* __restrict__ Z, const float* __restrict__ gstats,
                         const float* __restrict__ gamma_p, const float* __restrict__ beta_p)
{
    __shared__ float s_sc[CDIM], s_sf[CDIM];
    if (threadIdx.x < CDIM) {
        int c = threadIdx.x;
        const float inv_n = 1.f / (float)NTOT;
        float mu  = gstats[c] * inv_n;
        float var = gstats[128 + c] * inv_n - mu*mu;
        float sc  = gamma_p[c] * rsqrtf(var + BNEPS);
        s_sc[c] = sc;
        s_sf[c] = beta_p[c] - mu*sc;
    }
    __syncthreads();
    int i4 = blockIdx.x * blockDim.x + threadIdx.x;
    if (i4 >= NTOT*32) return;
    float4 z = ((const float4*)Z)[i4];
    int c = (i4 & 31) * 4;
    z.x = fmaxf(fmaf(z.x, s_sc[c+0], s_sf[c+0]), 0.f);
    z.y = fmaxf(fmaf(z.y, s_sc[c+1], s_sf[c+1]), 0.f);
    z.z = fmaxf(fmaf(z.z, s_sc[c+2], s_sf[c+2]), 0.f);
    z.w = fmaxf(fmaf(z.w, s_sc[c+3], s_sf[c+3]), 0.f);
    ((float4*)Z)[i4] = z;
}

extern "C" void kernel_launch(void* const* d_in, const int* in_sizes, int n_in,
                              void* d_out, int out_size, void* d_ws, size_t ws_size,
                              hipStream_t stream)
{
    (void)in_sizes; (void)n_in; (void)out_size; (void)ws_size;
    const float* h_f  = (const float*)d_in[0];
    const float* x_f  = (const float*)d_in[1];
    const float* x_c  = (const float*)d_in[2];
    const float* h_c  = (const float*)d_in[3];
    const float* Wv   = (const float*)d_in[6];
    const float* Wo   = (const float*)d_in[7];
    const float* bo   = (const float*)d_in[8];
    const float* ga   = (const float*)d_in[9];
    const float* ba   = (const float*)d_in[10];
    const float* Wp   = (const float*)d_in[11];
    const float* bp   = (const float*)d_in[12];
    const float* gp   = (const float*)d_in[13];
    const float* betp = (const float*)d_in[14];

    char*  ws     = (char*)d_ws;
    float* W1     = (float*)ws;                        // 65536 B
    float* cstats = (float*)(ws + 65536);              // 19*256*4 = 19456 B
    float* gstats = (float*)(ws + 65536 + 19456);      // 1024 B
    int*   tidx   = (int*)(ws + 65536 + 20480);        // 50000*5*4 = 1,000,000 B
    float* A      = (float*)(ws + 65536 + 20480 + 1000000); // 25.6 MB
    float* Z      = (float*)d_out;

    hipMemsetAsync(ws + 65536, 0, 20480, stream);      // zero cstats + gstats

    k1_w1    <<<dim3(CDIM),        dim3(CDIM), 0, stream>>>(Wv, Wo, W1);
    k2_topk  <<<dim3(43, NCHUNKS), dim3(256),  0, stream>>>(x_c, h_c, tidx);
    k3_gemm1 <<<dim3(43, NCHUNKS), dim3(256),  0, stream>>>(x_f, h_f, tidx, W1, bo, A);
    k4_cstats<<<dim3(22, NCHUNKS), dim3(256),  0, stream>>>(A, cstats);
    k5_gemm2 <<<dim3(43, NCHUNKS), dim3(256),  0, stream>>>(A, Wp, bp, ga, ba, cstats, Z);
    k6_gstats<<<dim3(391),         dim3(256),  0, stream>>>(Z, gstats);
    k7_final <<<dim3((NTOT*32 + 255)/256), dim3(256), 0, stream>>>(Z, gstats, gp, betp);
}

// Round 6
// 288.751 us; speedup vs baseline: 1.7884x; 1.2529x over previous
//
#include <hip/hip_runtime.h>
#include <hip/hip_bf16.h>
#include <math.h>

#define NTOT    50000
#define CDIM    128
#define FCHUNK  2714
#define MCH     18
#define NREM    (NTOT - MCH*FCHUNK)   /* 1148 */
#define NCHUNKS 19
#define TOPKN   5
#define INNERD  512
#define BNEPS   1e-5f
#define SEGS    8

static __device__ __forceinline__ int chunk_n(int chunk) {
    return (chunk < MCH) ? FCHUNK : NREM;
}

// strict-> sorted insert == lax.top_k stable tie-break
#define INS5(s, jj, V0,V1,V2,V3,V4,I0,I1,I2,I3,I4) \
    if (s > V4) { \
        if (s > V0)      { V4=V3;I4=I3; V3=V2;I3=I2; V2=V1;I2=I1; V1=V0;I1=I0; V0=s;I0=jj; } \
        else if (s > V1) { V4=V3;I4=I3; V3=V2;I3=I2; V2=V1;I2=I1; V1=s;I1=jj; } \
        else if (s > V2) { V4=V3;I4=I3; V3=V2;I3=I2; V2=s;I2=jj; } \
        else if (s > V3) { V4=V3;I4=I3; V3=s;I3=jj; } \
        else             { V4=s;I4=jj; } \
    }

#define CAS(x, y) { float lo_ = fminf(x, y), hi_ = fmaxf(x, y); x = lo_; y = hi_; }

// ---------------- K1: W1 = Wv @ Wo  (128x512 @ 512x128) ----------------
__global__ void k1_w1(const float* __restrict__ Wv, const float* __restrict__ Wo,
                      float* __restrict__ W1)
{
    __shared__ float s_wv[INNERD];
    int r = blockIdx.x;
    for (int t = threadIdx.x; t < INNERD; t += blockDim.x) s_wv[t] = Wv[r*INNERD + t];
    __syncthreads();
    int c = threadIdx.x;
    float acc = 0.f;
    #pragma unroll 8
    for (int k = 0; k < INNERD; ++k) acc = fmaf(s_wv[k], Wo[k*CDIM + c], acc);
    W1[r*CDIM + c] = acc;
}

// ------- K2: per-chunk top-5, two-pass (threshold) + batch-8 scan -------
__global__ __launch_bounds__(256) void k2_topk(const float* __restrict__ x_c,
                                               const float* __restrict__ h_c,
                                               int* __restrict__ tidx)
{
    __shared__ float4 sx4[FCHUNK];            // 43424 B; reused for merge
    __shared__ float  s_segmax[64][SEGS];
    __shared__ float  s_thr[64];
    int chunk = blockIdx.y;
    int base  = chunk * FCHUNK;
    int n     = chunk_n(chunk);
    int row0  = blockIdx.x * 64;
    if (row0 >= n) return;

    for (int t = threadIdx.x; t < n; t += 256)
        sx4[t] = make_float4(x_c[(base+t)*3], x_c[(base+t)*3+1], x_c[(base+t)*3+2], 0.f);
    __syncthreads();

    int seg = threadIdx.x & 7;
    int g   = threadIdx.x >> 3;               // 0..31
    int seglen = ((n + SEGS - 1) / SEGS) | 1; // odd -> distinct LDS banks per seg
    int j0 = seg*seglen, j1 = min(n, j0 + seglen);

    int rA = row0 + g, rB = row0 + g + 32;
    bool vA = rA < n, vB = rB < n;
    float hA0=0,hA1=0,hA2=0,hB0=0,hB1=0,hB2=0;
    if (vA){ hA0=h_c[(base+rA)*3]; hA1=h_c[(base+rA)*3+1]; hA2=h_c[(base+rA)*3+2]; }
    if (vB){ hB0=h_c[(base+rB)*3]; hB1=h_c[(base+rB)*3+1]; hB2=h_c[(base+rB)*3+2]; }

    // ---- pass 1: branchless segment maxes ----
    float mA = -INFINITY, mB = -INFINITY;
    int j = j0;
    for (; j + 8 <= j1; j += 8) {
        #pragma unroll
        for (int k = 0; k < 8; ++k) {
            float4 x = sx4[j+k];
            float dA = fmaf(x.z,hA2, fmaf(x.y,hA1, x.x*hA0));
            float dB = fmaf(x.z,hB2, fmaf(x.y,hB1, x.x*hB0));
            mA = fmaxf(mA, dA); mB = fmaxf(mB, dB);
        }
    }
    for (; j < j1; ++j) {
        float4 x = sx4[j];
        mA = fmaxf(mA, fmaf(x.z,hA2, fmaf(x.y,hA1, x.x*hA0)));
        mB = fmaxf(mB, fmaf(x.z,hB2, fmaf(x.y,hB1, x.x*hB0)));
    }
    s_segmax[g][seg]    = mA;
    s_segmax[g+32][seg] = mB;
    __syncthreads();

    // ---- threshold: 5th largest of 8 segment maxes (sound: m5 <= v5) ----
    if (threadIdx.x < 64) {
        int lr = threadIdx.x;
        float a0 = s_segmax[lr][0], a1 = s_segmax[lr][1], a2 = s_segmax[lr][2], a3 = s_segmax[lr][3];
        float a4 = s_segmax[lr][4], a5 = s_segmax[lr][5], a6 = s_segmax[lr][6], a7 = s_segmax[lr][7];
        CAS(a0,a1); CAS(a2,a3); CAS(a4,a5); CAS(a6,a7);
        CAS(a0,a2); CAS(a1,a3); CAS(a4,a6); CAS(a5,a7);
        CAS(a1,a2); CAS(a5,a6);
        CAS(a0,a4); CAS(a1,a5); CAS(a2,a6); CAS(a3,a7);
        CAS(a2,a4); CAS(a3,a5);
        CAS(a1,a2); CAS(a3,a4); CAS(a5,a6);
        s_thr[lr] = (row0 + lr < n) ? a3 : INFINITY;   // ascending[3] = 5th largest
    }
    __syncthreads();
    float thrA = s_thr[g], thrB = s_thr[g+32];

    // ---- pass 2: filtered scan, identical fma order -> identical bits ----
    float aV0=-INFINITY,aV1=-INFINITY,aV2=-INFINITY,aV3=-INFINITY,aV4=-INFINITY;
    float bV0=-INFINITY,bV1=-INFINITY,bV2=-INFINITY,bV3=-INFINITY,bV4=-INFINITY;
    int aI0=0,aI1=0,aI2=0,aI3=0,aI4=0, bI0=0,bI1=0,bI2=0,bI3=0,bI4=0;

    j = j0;
    for (; j + 8 <= j1; j += 8) {
        float dA[8], dB[8];
        float gA = -INFINITY, gB = -INFINITY;
        #pragma unroll
        for (int k = 0; k < 8; ++k) {
            float4 x = sx4[j+k];
            dA[k] = fmaf(x.z,hA2, fmaf(x.y,hA1, x.x*hA0));
            dB[k] = fmaf(x.z,hB2, fmaf(x.y,hB1, x.x*hB0));
            gA = fmaxf(gA, dA[k]); gB = fmaxf(gB, dB[k]);
        }
        bool tA = !(gA < thrA), tB = !(gB < thrB);
        if (tA || tB) {
            #pragma unroll
            for (int k = 0; k < 8; ++k) {
                if (tA && !(dA[k] < thrA)) { INS5(dA[k], (j+k), aV0,aV1,aV2,aV3,aV4, aI0,aI1,aI2,aI3,aI4); }
                if (tB && !(dB[k] < thrB)) { INS5(dB[k], (j+k), bV0,bV1,bV2,bV3,bV4, bI0,bI1,bI2,bI3,bI4); }
            }
        }
    }
    for (; j < j1; ++j) {
        float4 x = sx4[j];
        float dA = fmaf(x.z,hA2, fmaf(x.y,hA1, x.x*hA0));
        float dB = fmaf(x.z,hB2, fmaf(x.y,hB1, x.x*hB0));
        if (!(dA < thrA)) { INS5(dA, j, aV0,aV1,aV2,aV3,aV4, aI0,aI1,aI2,aI3,aI4); }
        if (!(dB < thrB)) { INS5(dB, j, bV0,bV1,bV2,bV3,bV4, bI0,bI1,bI2,bI3,bI4); }
    }
    __syncthreads();                          // done reading sx4; reuse as merge buf

    float* cv = (float*)sx4;                  // [64][8][5] values
    int*   ci = (int*)(cv + 64*40);           // [64][8][5] indices
    int offA = (g*8 + seg)*5;
    int offB = ((g+32)*8 + seg)*5;
    cv[offA+0]=aV0; cv[offA+1]=aV1; cv[offA+2]=aV2; cv[offA+3]=aV3; cv[offA+4]=aV4;
    ci[offA+0]=aI0; ci[offA+1]=aI1; ci[offA+2]=aI2; ci[offA+3]=aI3; ci[offA+4]=aI4;
    cv[offB+0]=bV0; cv[offB+1]=bV1; cv[offB+2]=bV2; cv[offB+3]=bV3; cv[offB+4]=bV4;
    ci[offB+0]=bI0; ci[offB+1]=bI1; ci[offB+2]=bI2; ci[offB+3]=bI3; ci[offB+4]=bI4;
    __syncthreads();

    if (threadIdx.x < 64) {
        int lr = threadIdx.x, row = row0 + lr;
        if (row < n) {
            float v0=-INFINITY,v1=-INFINITY,v2=-INFINITY,v3=-INFINITY,v4=-INFINITY;
            int i0=0,i1=0,i2=0,i3=0,i4=0;
            for (int t = 0; t < 40; ++t) {    // segment order == ascending j -> stable ties
                float s = cv[lr*40 + t]; int jj = ci[lr*40 + t];
                INS5(s, jj, v0,v1,v2,v3,v4, i0,i1,i2,i3,i4);
            }
            int o = (base+row)*TOPKN;
            tidx[o+0]=i0; tidx[o+1]=i1; tidx[o+2]=i2; tidx[o+3]=i3; tidx[o+4]=i4;
        }
    }
}

// ------- K3: scramble + gather + hsum, then A = hsum @ W1 + bo -------
__global__ __launch_bounds__(256) void k3_gemm1(const float* __restrict__ x_f,
                         const float* __restrict__ h_f,
                         const int* __restrict__ tidx, const float* __restrict__ W1,
                         const float* __restrict__ bo, float* __restrict__ A)
{
    __shared__ float s_h[64][132];
    __shared__ float s_w[32][128];
    __shared__ int   s_nb[64][TOPKN];
    int chunk = blockIdx.y;
    int base  = chunk * FCHUNK;
    int n     = chunk_n(chunk);
    int row0  = blockIdx.x * 64;
    if (row0 >= n) return;

    for (int e = threadIdx.x; e < 64*TOPKN; e += 256) {
        int r = e / TOPKN, k = e % TOPKN;
        int il = row0 + r;
        int nb = 0;
        if (il < n) {
            int p = il*TOPKN + k;             // faithful tidx.T flatten order
            int q, m;
            if (n == FCHUNK) { q = p / FCHUNK; m = p - q*FCHUNK; }
            else             { q = p / NREM;   m = p - q*NREM; }
            nb = tidx[(base + m)*TOPKN + q];
        }
        s_nb[r][k] = nb;
    }
    __syncthreads();

    for (int e = threadIdx.x; e < 64*32; e += 256) {
        int r = e >> 5, c4 = e & 31;
        float4 acc4 = make_float4(0.f,0.f,0.f,0.f);
        int gr = row0 + r;
        if (gr < n) {
            acc4 = *(const float4*)&x_f[(base+gr)*CDIM + c4*4];
            #pragma unroll
            for (int k = 0; k < TOPKN; ++k) {
                float4 h4 = *(const float4*)&h_f[(base + s_nb[r][k])*CDIM + c4*4];
                acc4.x += h4.x; acc4.y += h4.y; acc4.z += h4.z; acc4.w += h4.w;
            }
        }
        *(float4*)&s_h[r][c4*4] = acc4;
    }

    float acc[4][8];
    #pragma unroll
    for (int i = 0; i < 4; ++i)
        #pragma unroll
        for (int j = 0; j < 8; ++j) acc[i][j] = 0.f;
    int tx = threadIdx.x & 15, ty = threadIdx.x >> 4;
    int c0 = tx*8, r0 = ty*4;

    for (int kt = 0; kt < CDIM; kt += 32) {
        __syncthreads();
        for (int e = threadIdx.x; e < 32*32; e += 256) {
            int kr = e >> 5, c4 = e & 31;
            *(float4*)&s_w[kr][c4*4] = *(const float4*)&W1[(kt+kr)*CDIM + c4*4];
        }
        __syncthreads();
        #pragma unroll
        for (int kk = 0; kk < 32; kk += 4) {
            float a[4][4];
            #pragma unroll
            for (int ri = 0; ri < 4; ++ri)
                *(float4*)a[ri] = *(const float4*)&s_h[r0+ri][kt+kk];
            #pragma unroll
            for (int dk = 0; dk < 4; ++dk) {
                float4 w0 = *(const float4*)&s_w[kk+dk][c0];
                float4 w1 = *(const float4*)&s_w[kk+dk][c0+4];
                #pragma unroll
                for (int ri = 0; ri < 4; ++ri) {
                    float av = a[ri][dk];
                    acc[ri][0]=fmaf(av,w0.x,acc[ri][0]); acc[ri][1]=fmaf(av,w0.y,acc[ri][1]);
                    acc[ri][2]=fmaf(av,w0.z,acc[ri][2]); acc[ri][3]=fmaf(av,w0.w,acc[ri][3]);
                    acc[ri][4]=fmaf(av,w1.x,acc[ri][4]); acc[ri][5]=fmaf(av,w1.y,acc[ri][5]);
                    acc[ri][6]=fmaf(av,w1.z,acc[ri][6]); acc[ri][7]=fmaf(av,w1.w,acc[ri][7]);
                }
            }
        }
    }

    #pragma unroll
    for (int ri = 0; ri < 4; ++ri) {
        int gr = row0 + r0 + ri;
        if (gr < n) {
            float* out = &A[(base+gr)*CDIM + c0];
            #pragma unroll
            for (int j = 0; j < 8; ++j) out[j] = acc[ri][j] + bo[c0 + j];
        }
    }
}

// ---------------- K4: per-chunk BN stats (sum, sumsq) ----------------
__global__ void k4_cstats(const float* __restrict__ A, float* __restrict__ cstats)
{
    int chunk = blockIdx.y;
    int base  = chunk * FCHUNK;
    int n     = chunk_n(chunk);
    int row0  = blockIdx.x * 128;
    if (row0 >= n) return;
    int nr = min(128, n - row0);
    int c    = threadIdx.x & 127;
    int half = threadIdx.x >> 7;
    float s = 0.f, s2 = 0.f;
    for (int rr = half; rr < nr; rr += 2) {
        float a = A[(base+row0+rr)*CDIM + c];
        s += a; s2 = fmaf(a, a, s2);
    }
    atomicAdd(&cstats[chunk*256 + c], s);
    atomicAdd(&cstats[chunk*256 + 128 + c], s2);
}

// ------- K5: Y = relu(BN_chunk(A)); Z = Y @ Wp + bp  (fused) -------
__global__ __launch_bounds__(256) void k5_gemm2(const float* __restrict__ A,
                         const float* __restrict__ Wp,
                         const float* __restrict__ bp, const float* __restrict__ gamma_a,
                         const float* __restrict__ beta_a, const float* __restrict__ cstats,
                         float* __restrict__ Z)
{
    __shared__ float s_h[64][132];
    __shared__ float s_w[32][128];
    __shared__ float s_sc[CDIM], s_sf[CDIM];
    int chunk = blockIdx.y;
    int base  = chunk * FCHUNK;
    int n     = chunk_n(chunk);
    int row0  = blockIdx.x * 64;
    if (row0 >= n) return;

    if (threadIdx.x < CDIM) {
        int c = threadIdx.x;
        float inv_n = 1.f / (float)n;
        float mu  = cstats[chunk*256 + c] * inv_n;
        float var = cstats[chunk*256 + 128 + c] * inv_n - mu*mu;
        float sc  = gamma_a[c] * rsqrtf(var + BNEPS);
        s_sc[c] = sc;
        s_sf[c] = beta_a[c] - mu*sc;
    }
    __syncthreads();

    for (int e = threadIdx.x; e < 64*32; e += 256) {
        int r = e >> 5, c4 = e & 31;
        float4 y = make_float4(0.f,0.f,0.f,0.f);
        int gr = row0 + r;
        if (gr < n) {
            float4 a4 = *(const float4*)&A[(base+gr)*CDIM + c4*4];
            int c = c4*4;
            y.x = fmaxf(fmaf(a4.x, s_sc[c+0], s_sf[c+0]), 0.f);
            y.y = fmaxf(fmaf(a4.y, s_sc[c+1], s_sf[c+1]), 0.f);
            y.z = fmaxf(fmaf(a4.z, s_sc[c+2], s_sf[c+2]), 0.f);
            y.w = fmaxf(fmaf(a4.w, s_sc[c+3], s_sf[c+3]), 0.f);
        }
        *(float4*)&s_h[r][c4*4] = y;
    }

    float acc[4][8];
    #pragma unroll
    for (int i = 0; i < 4; ++i)
        #pragma unroll
        for (int j = 0; j < 8; ++j) acc[i][j] = 0.f;
    int tx = threadIdx.x & 15, ty = threadIdx.x >> 4;
    int c0 = tx*8, r0 = ty*4;

    for (int kt = 0; kt < CDIM; kt += 32) {
        __syncthreads();
        for (int e = threadIdx.x; e < 32*32; e += 256) {
            int kr = e >> 5, c4 = e & 31;
            *(float4*)&s_w[kr][c4*4] = *(const float4*)&Wp[(kt+kr)*CDIM + c4*4];
        }
        __syncthreads();
        #pragma unroll
        for (int kk = 0; kk < 32; kk += 4) {
            float a[4][4];
            #pragma unroll
            for (int ri = 0; ri < 4; ++ri)
                *(float4*)a[ri] = *(const float4*)&s_h[r0+ri][kt+kk];
            #pragma unroll
            for (int dk = 0; dk < 4; ++dk) {
                float4 w0 = *(const float4*)&s_w[kk+dk][c0];
                float4 w1 = *(const float4*)&s_w[kk+dk][c0+4];
                #pragma unroll
                for (int ri = 0; ri < 4; ++ri) {
                    float av = a[ri][dk];
                    acc[ri][0]=fmaf(av,w0.x,acc[ri][0]); acc[ri][1]=fmaf(av,w0.y,acc[ri][1]);
                    acc[ri][2]=fmaf(av,w0.z,acc[ri][2]); acc[ri][3]=fmaf(av,w0.w,acc[ri][3]);
                    acc[ri][4]=fmaf(av,w1.x,acc[ri][4]); acc[ri][5]=fmaf(av,w1.y,acc[ri][5]);
                    acc[ri][6]=fmaf(av,w1.z,acc[ri][6]); acc[ri][7]=fmaf(av,w1.w,acc[ri][7]);
                }
            }
        }
    }

    #pragma unroll
    for (int ri = 0; ri < 4; ++ri) {
        int gr = row0 + r0 + ri;
        if (gr < n) {
            float* out = &Z[(base+gr)*CDIM + c0];
            #pragma unroll
            for (int j = 0; j < 8; ++j) out[j] = acc[ri][j] + bp[c0 + j];
        }
    }
}

// ---------------- K6: global BN stats ----------------
__global__ void k6_gstats(const float* __restrict__ Z, float* __restrict__ gstats)
{
    int row0 = blockIdx.x * 128;
    if (row0 >= NTOT) return;
    int nr = min(128, NTOT - row0);
    int c    = threadIdx.x & 127;
    int half = threadIdx.x >> 7;
    float s = 0.f, s2 = 0.f;
    for (int rr = half; rr < nr; rr += 2) {
        float a = Z[(row0+rr)*CDIM + c];
        s += a; s2 = fmaf(a, a, s2);
    }
    atomicAdd(&gstats[c], s);
    atomicAdd(&gstats[128 + c], s2);
}

// ---------------- K7: final BN + ReLU in place (float4) ----------------
__global__ void k7_final(float* __restrict__ Z, const float* __restrict__ gstats,
                         const float* __restrict__ gamma_p, const float* __restrict__ beta_p)
{
    __shared__ float s_sc[CDIM], s_sf[CDIM];
    if (threadIdx.x < CDIM) {
        int c = threadIdx.x;
        const float inv_n = 1.f / (float)NTOT;
        float mu  = gstats[c] * inv_n;
        float var = gstats[128 + c] * inv_n - mu*mu;
        float sc  = gamma_p[c] * rsqrtf(var + BNEPS);
        s_sc[c] = sc;
        s_sf[c] = beta_p[c] - mu*sc;
    }
    __syncthreads();
    int i4 = blockIdx.x * blockDim.x + threadIdx.x;
    if (i4 >= NTOT*32) return;
    float4 z = ((const float4*)Z)[i4];
    int c = (i4 & 31) * 4;
    z.x = fmaxf(fmaf(z.x, s_sc[c+0], s_sf[c+0]), 0.f);
    z.y = fmaxf(fmaf(z.y, s_sc[c+1], s_sf[c+1]), 0.f);
    z.z = fmaxf(fmaf(z.z, s_sc[c+2], s_sf[c+2]), 0.f);
    z.w = fmaxf(fmaf(z.w, s_sc[c+3], s_sf[c+3]), 0.f);
    ((float4*)Z)[i4] = z;
}

extern "C" void kernel_launch(void* const* d_in, const int* in_sizes, int n_in,
                              void* d_out, int out_size, void* d_ws, size_t ws_size,
                              hipStream_t stream)
{
    (void)in_sizes; (void)n_in; (void)out_size; (void)ws_size;
    const float* h_f  = (const float*)d_in[0];
    const float* x_f  = (const float*)d_in[1];
    const float* x_c  = (const float*)d_in[2];
    const float* h_c  = (const float*)d_in[3];
    const float* Wv   = (const float*)d_in[6];
    const float* Wo   = (const float*)d_in[7];
    const float* bo   = (const float*)d_in[8];
    const float* ga   = (const float*)d_in[9];
    const float* ba   = (const float*)d_in[10];
    const float* Wp   = (const float*)d_in[11];
    const float* bp   = (const float*)d_in[12];
    const float* gp   = (const float*)d_in[13];
    const float* betp = (const float*)d_in[14];

    char*  ws     = (char*)d_ws;
    float* W1     = (float*)ws;                        // 65536 B
    float* cstats = (float*)(ws + 65536);              // 19*256*4 = 19456 B
    float* gstats = (float*)(ws + 65536 + 19456);      // 1024 B
    int*   tidx   = (int*)(ws + 65536 + 20480);        // 50000*5*4 = 1,000,000 B
    float* A      = (float*)(ws + 65536 + 20480 + 1000000); // 25.6 MB
    float* Z      = (float*)d_out;

    hipMemsetAsync(ws + 65536, 0, 20480, stream);      // zero cstats + gstats

    k1_w1    <<<dim3(CDIM),        dim3(CDIM), 0, stream>>>(Wv, Wo, W1);
    k2_topk  <<<dim3(43, NCHUNKS), dim3(256),  0, stream>>>(x_c, h_c, tidx);
    k3_gemm1 <<<dim3(43, NCHUNKS), dim3(256),  0, stream>>>(x_f, h_f, tidx, W1, bo, A);
    k4_cstats<<<dim3(22, NCHUNKS), dim3(256),  0, stream>>>(A, cstats);
    k5_gemm2 <<<dim3(43, NCHUNKS), dim3(256),  0, stream>>>(A, Wp, bp, ga, ba, cstats, Z);
    k6_gstats<<<dim3(391),         dim3(256),  0, stream>>>(Z, gstats);
    k7_final <<<dim3((NTOT*32 + 255)/256), dim3(256), 0, stream>>>(Z, gstats, gp, betp);
}

// Round 7
// 280.632 us; speedup vs baseline: 1.8401x; 1.0289x over previous
//
#include <hip/hip_runtime.h>
#include <hip/hip_bf16.h>
#include <math.h>

#define NTOT    50000
#define CDIM    128
#define FCHUNK  2714
#define MCH     18
#define NREM    (NTOT - MCH*FCHUNK)   /* 1148 */
#define NCHUNKS 19
#define TOPKN   5
#define INNERD  512
#define BNEPS   1e-5f
#define SEGS    8
#define CAP     25

static __device__ __forceinline__ int chunk_n(int chunk) {
    return (chunk < MCH) ? FCHUNK : NREM;
}

// strict-> sorted insert == lax.top_k stable tie-break (ascending-j stream)
#define INS5(s, jj, V0,V1,V2,V3,V4,I0,I1,I2,I3,I4) \
    if (s > V4) { \
        if (s > V0)      { V4=V3;I4=I3; V3=V2;I3=I2; V2=V1;I2=I1; V1=V0;I1=I0; V0=s;I0=jj; } \
        else if (s > V1) { V4=V3;I4=I3; V3=V2;I3=I2; V2=V1;I2=I1; V1=s;I1=jj; } \
        else if (s > V2) { V4=V3;I4=I3; V3=V2;I3=I2; V2=s;I2=jj; } \
        else if (s > V3) { V4=V3;I4=I3; V3=s;I3=jj; } \
        else             { V4=s;I4=jj; } \
    }

// composite (val desc, idx asc) insert — order-independent == stable top-k
#define INS5C(s, jj, V0,V1,V2,V3,V4,I0,I1,I2,I3,I4) \
    if ((s > V4) || (s == V4 && jj < I4)) { \
        if ((s > V0) || (s == V0 && jj < I0))      { V4=V3;I4=I3; V3=V2;I3=I2; V2=V1;I2=I1; V1=V0;I1=I0; V0=s;I0=jj; } \
        else if ((s > V1) || (s == V1 && jj < I1)) { V4=V3;I4=I3; V3=V2;I3=I2; V2=V1;I2=I1; V1=s;I1=jj; } \
        else if ((s > V2) || (s == V2 && jj < I2)) { V4=V3;I4=I3; V3=V2;I3=I2; V2=s;I2=jj; } \
        else if ((s > V3) || (s == V3 && jj < I3)) { V4=V3;I4=I3; V3=s;I3=jj; } \
        else                                        { V4=s;I4=jj; } \
    }

#define CAS(x, y) { float lo_ = fminf(x, y), hi_ = fmaxf(x, y); x = lo_; y = hi_; }

// ---------------- K1: W1 = Wv @ Wo  (128x512 @ 512x128) ----------------
__global__ void k1_w1(const float* __restrict__ Wv, const float* __restrict__ Wo,
                      float* __restrict__ W1)
{
    __shared__ float s_wv[INNERD];
    int r = blockIdx.x;
    for (int t = threadIdx.x; t < INNERD; t += blockDim.x) s_wv[t] = Wv[r*INNERD + t];
    __syncthreads();
    int c = threadIdx.x;
    float acc = 0.f;
    #pragma unroll 8
    for (int k = 0; k < INNERD; ++k) acc = fmaf(s_wv[k], Wo[k*CDIM + c], acc);
    W1[r*CDIM + c] = acc;
}

// --- K2: per-chunk top-5: threshold pass + candidate-append + tiny merge ---
__global__ __launch_bounds__(256) void k2_topk(const float* __restrict__ x_c,
                                               const float* __restrict__ h_c,
                                               int* __restrict__ tidx)
{
    __shared__ float s_xf[FCHUNK*3];          // 32568 B, packed float3
    __shared__ float scratch[3264];           // overlay: segmax/thr then cnt/cv/cj
    int chunk = blockIdx.y;
    int base  = chunk * FCHUNK;
    int n     = chunk_n(chunk);
    int row0  = blockIdx.x * 64;
    if (row0 >= n) return;

    for (int e = threadIdx.x; e < n*3; e += 256) s_xf[e] = x_c[base*3 + e];
    __syncthreads();

    int seg = threadIdx.x & 7;
    int g   = threadIdx.x >> 3;               // 0..31
    int seglen = ((n + SEGS - 1) / SEGS) | 1; // odd -> distinct LDS banks per seg
    int j0 = seg*seglen, j1 = min(n, j0 + seglen);

    int rA = row0 + g, rB = row0 + g + 32;
    float hA0=0,hA1=0,hA2=0,hB0=0,hB1=0,hB2=0;
    if (rA < n){ hA0=h_c[(base+rA)*3]; hA1=h_c[(base+rA)*3+1]; hA2=h_c[(base+rA)*3+2]; }
    if (rB < n){ hB0=h_c[(base+rB)*3]; hB1=h_c[(base+rB)*3+1]; hB2=h_c[(base+rB)*3+2]; }

    // ---- pass 1: branchless segment maxes ----
    float* s_segmax = scratch;                // [64][8]
    float* s_thr    = scratch + 512;          // [64]
    float mA = -INFINITY, mB = -INFINITY;
    int j = j0;
    for (; j + 8 <= j1; j += 8) {
        #pragma unroll
        for (int k = 0; k < 8; ++k) {
            float xx = s_xf[(j+k)*3], xy = s_xf[(j+k)*3+1], xz = s_xf[(j+k)*3+2];
            mA = fmaxf(mA, fmaf(xz,hA2, fmaf(xy,hA1, xx*hA0)));
            mB = fmaxf(mB, fmaf(xz,hB2, fmaf(xy,hB1, xx*hB0)));
        }
    }
    for (; j < j1; ++j) {
        float xx = s_xf[j*3], xy = s_xf[j*3+1], xz = s_xf[j*3+2];
        mA = fmaxf(mA, fmaf(xz,hA2, fmaf(xy,hA1, xx*hA0)));
        mB = fmaxf(mB, fmaf(xz,hB2, fmaf(xy,hB1, xx*hB0)));
    }
    s_segmax[g*SEGS + seg]      = mA;
    s_segmax[(g+32)*SEGS + seg] = mB;
    __syncthreads();

    // ---- threshold: 5th largest of 8 segment maxes (sound: T <= v5) ----
    if (threadIdx.x < 64) {
        int lr = threadIdx.x;
        float a0 = s_segmax[lr*SEGS+0], a1 = s_segmax[lr*SEGS+1], a2 = s_segmax[lr*SEGS+2], a3 = s_segmax[lr*SEGS+3];
        float a4 = s_segmax[lr*SEGS+4], a5 = s_segmax[lr*SEGS+5], a6 = s_segmax[lr*SEGS+6], a7 = s_segmax[lr*SEGS+7];
        CAS(a0,a1); CAS(a2,a3); CAS(a4,a5); CAS(a6,a7);
        CAS(a0,a2); CAS(a1,a3); CAS(a4,a6); CAS(a5,a7);
        CAS(a1,a2); CAS(a5,a6);
        CAS(a0,a4); CAS(a1,a5); CAS(a2,a6); CAS(a3,a7);
        CAS(a2,a4); CAS(a3,a5);
        CAS(a1,a2); CAS(a3,a4); CAS(a5,a6);
        s_thr[lr] = (row0 + lr < n) ? a3 : INFINITY;   // ascending[3] = 5th largest
    }
    __syncthreads();
    float thrA = s_thr[g], thrB = s_thr[g+32];
    __syncthreads();                          // thr consumed; scratch may be reused

    // ---- overlay phase B: candidate buffers ----
    int*   s_cnt = (int*)scratch;             // [64]
    float* s_cv  = scratch + 64;              // [64][CAP]
    int*   s_cj  = (int*)(scratch + 64 + 64*CAP); // [64][CAP]
    if (threadIdx.x < 64) s_cnt[threadIdx.x] = 0;
    __syncthreads();

    // ---- pass 2: append candidates >= thr (identical fma order -> exact bits) ----
    j = j0;
    for (; j + 8 <= j1; j += 8) {
        #pragma unroll
        for (int k = 0; k < 8; ++k) {
            float xx = s_xf[(j+k)*3], xy = s_xf[(j+k)*3+1], xz = s_xf[(j+k)*3+2];
            float dA = fmaf(xz,hA2, fmaf(xy,hA1, xx*hA0));
            float dB = fmaf(xz,hB2, fmaf(xy,hB1, xx*hB0));
            if (!(dA < thrA)) { int p = atomicAdd(&s_cnt[g], 1);
                                if (p < CAP) { s_cv[g*CAP+p] = dA; s_cj[g*CAP+p] = j+k; } }
            if (!(dB < thrB)) { int p = atomicAdd(&s_cnt[g+32], 1);
                                if (p < CAP) { s_cv[(g+32)*CAP+p] = dB; s_cj[(g+32)*CAP+p] = j+k; } }
        }
    }
    for (; j < j1; ++j) {
        float xx = s_xf[j*3], xy = s_xf[j*3+1], xz = s_xf[j*3+2];
        float dA = fmaf(xz,hA2, fmaf(xy,hA1, xx*hA0));
        float dB = fmaf(xz,hB2, fmaf(xy,hB1, xx*hB0));
        if (!(dA < thrA)) { int p = atomicAdd(&s_cnt[g], 1);
                            if (p < CAP) { s_cv[g*CAP+p] = dA; s_cj[g*CAP+p] = j; } }
        if (!(dB < thrB)) { int p = atomicAdd(&s_cnt[g+32], 1);
                            if (p < CAP) { s_cv[(g+32)*CAP+p] = dB; s_cj[(g+32)*CAP+p] = j; } }
    }
    __syncthreads();

    // ---- merge: composite top-5 over ~7 candidates per row ----
    if (threadIdx.x < 64) {
        int lr = threadIdx.x, row = row0 + lr;
        if (row < n) {
            float v0=-INFINITY,v1=-INFINITY,v2=-INFINITY,v3=-INFINITY,v4=-INFINITY;
            int i0=0x7fffffff,i1=0x7fffffff,i2=0x7fffffff,i3=0x7fffffff,i4=0x7fffffff;
            int m = s_cnt[lr];
            if (m <= CAP) {
                for (int t = 0; t < m; ++t) {
                    float s = s_cv[lr*CAP + t]; int jj = s_cj[lr*CAP + t];
                    INS5C(s, jj, v0,v1,v2,v3,v4, i0,i1,i2,i3,i4);
                }
            } else {
                // overflow fallback (expected never): serial ascending-j rescan
                float h0 = h_c[(base+row)*3], h1 = h_c[(base+row)*3+1], h2 = h_c[(base+row)*3+2];
                v0=v1=v2=v3=v4=-INFINITY; i0=i1=i2=i3=i4=0;
                for (int jj = 0; jj < n; ++jj) {
                    float s = fmaf(s_xf[jj*3+2],h2, fmaf(s_xf[jj*3+1],h1, s_xf[jj*3]*h0));
                    INS5(s, jj, v0,v1,v2,v3,v4, i0,i1,i2,i3,i4);
                }
            }
            int o = (base+row)*TOPKN;
            tidx[o+0]=i0; tidx[o+1]=i1; tidx[o+2]=i2; tidx[o+3]=i3; tidx[o+4]=i4;
        }
    }
}

// ------- K3: scramble + gather + hsum, then A = hsum @ W1 + bo -------
__global__ __launch_bounds__(256) void k3_gemm1(const float* __restrict__ x_f,
                         const float* __restrict__ h_f,
                         const int* __restrict__ tidx, const float* __restrict__ W1,
                         const float* __restrict__ bo, float* __restrict__ A)
{
    __shared__ float s_h[64][132];
    __shared__ float s_w[32][128];
    __shared__ int   s_nb[64][TOPKN];
    int chunk = blockIdx.y;
    int base  = chunk * FCHUNK;
    int n     = chunk_n(chunk);
    int row0  = blockIdx.x * 64;
    if (row0 >= n) return;

    for (int e = threadIdx.x; e < 64*TOPKN; e += 256) {
        int r = e / TOPKN, k = e % TOPKN;
        int il = row0 + r;
        int nb = 0;
        if (il < n) {
            int p = il*TOPKN + k;             // faithful tidx.T flatten order
            int q, m;
            if (n == FCHUNK) { q = p / FCHUNK; m = p - q*FCHUNK; }
            else             { q = p / NREM;   m = p - q*NREM; }
            nb = tidx[(base + m)*TOPKN + q];
        }
        s_nb[r][k] = nb;
    }
    __syncthreads();

    for (int e = threadIdx.x; e < 64*32; e += 256) {
        int r = e >> 5, c4 = e & 31;
        float4 acc4 = make_float4(0.f,0.f,0.f,0.f);
        int gr = row0 + r;
        if (gr < n) {
            acc4 = *(const float4*)&x_f[(base+gr)*CDIM + c4*4];
            #pragma unroll
            for (int k = 0; k < TOPKN; ++k) {
                float4 h4 = *(const float4*)&h_f[(base + s_nb[r][k])*CDIM + c4*4];
                acc4.x += h4.x; acc4.y += h4.y; acc4.z += h4.z; acc4.w += h4.w;
            }
        }
        *(float4*)&s_h[r][c4*4] = acc4;
    }

    float acc[4][8];
    #pragma unroll
    for (int i = 0; i < 4; ++i)
        #pragma unroll
        for (int j = 0; j < 8; ++j) acc[i][j] = 0.f;
    int tx = threadIdx.x & 15, ty = threadIdx.x >> 4;
    int c0 = tx*8, r0 = ty*4;

    for (int kt = 0; kt < CDIM; kt += 32) {
        __syncthreads();
        for (int e = threadIdx.x; e < 32*32; e += 256) {
            int kr = e >> 5, c4 = e & 31;
            *(float4*)&s_w[kr][c4*4] = *(const float4*)&W1[(kt+kr)*CDIM + c4*4];
        }
        __syncthreads();
        #pragma unroll
        for (int kk = 0; kk < 32; kk += 4) {
            float a[4][4];
            #pragma unroll
            for (int ri = 0; ri < 4; ++ri)
                *(float4*)a[ri] = *(const float4*)&s_h[r0+ri][kt+kk];
            #pragma unroll
            for (int dk = 0; dk < 4; ++dk) {
                float4 w0 = *(const float4*)&s_w[kk+dk][c0];
                float4 w1 = *(const float4*)&s_w[kk+dk][c0+4];
                #pragma unroll
                for (int ri = 0; ri < 4; ++ri) {
                    float av = a[ri][dk];
                    acc[ri][0]=fmaf(av,w0.x,acc[ri][0]); acc[ri][1]=fmaf(av,w0.y,acc[ri][1]);
                    acc[ri][2]=fmaf(av,w0.z,acc[ri][2]); acc[ri][3]=fmaf(av,w0.w,acc[ri][3]);
                    acc[ri][4]=fmaf(av,w1.x,acc[ri][4]); acc[ri][5]=fmaf(av,w1.y,acc[ri][5]);
                    acc[ri][6]=fmaf(av,w1.z,acc[ri][6]); acc[ri][7]=fmaf(av,w1.w,acc[ri][7]);
                }
            }
        }
    }

    #pragma unroll
    for (int ri = 0; ri < 4; ++ri) {
        int gr = row0 + r0 + ri;
        if (gr < n) {
            float* out = &A[(base+gr)*CDIM + c0];
            #pragma unroll
            for (int j = 0; j < 8; ++j) out[j] = acc[ri][j] + bo[c0 + j];
        }
    }
}

// ---------------- K4: per-chunk BN stats (sum, sumsq) ----------------
__global__ void k4_cstats(const float* __restrict__ A, float* __restrict__ cstats)
{
    int chunk = blockIdx.y;
    int base  = chunk * FCHUNK;
    int n     = chunk_n(chunk);
    int row0  = blockIdx.x * 128;
    if (row0 >= n) return;
    int nr = min(128, n - row0);
    int c    = threadIdx.x & 127;
    int half = threadIdx.x >> 7;
    float s = 0.f, s2 = 0.f;
    for (int rr = half; rr < nr; rr += 2) {
        float a = A[(base+row0+rr)*CDIM + c];
        s += a; s2 = fmaf(a, a, s2);
    }
    atomicAdd(&cstats[chunk*256 + c], s);
    atomicAdd(&cstats[chunk*256 + 128 + c], s2);
}

// ------- K5: Y = relu(BN_chunk(A)); Z = Y @ Wp + bp  (fused) -------
__global__ __launch_bounds__(256) void k5_gemm2(const float* __restrict__ A,
                         const float* __restrict__ Wp,
                         const float* __restrict__ bp, const float* __restrict__ gamma_a,
                         const float* __restrict__ beta_a, const float* __restrict__ cstats,
                         float* __restrict__ Z)
{
    __shared__ float s_h[64][132];
    __shared__ float s_w[32][128];
    __shared__ float s_sc[CDIM], s_sf[CDIM];
    int chunk = blockIdx.y;
    int base  = chunk * FCHUNK;
    int n     = chunk_n(chunk);
    int row0  = blockIdx.x * 64;
    if (row0 >= n) return;

    if (threadIdx.x < CDIM) {
        int c = threadIdx.x;
        float inv_n = 1.f / (float)n;
        float mu  = cstats[chunk*256 + c] * inv_n;
        float var = cstats[chunk*256 + 128 + c] * inv_n - mu*mu;
        float sc  = gamma_a[c] * rsqrtf(var + BNEPS);
        s_sc[c] = sc;
        s_sf[c] = beta_a[c] - mu*sc;
    }
    __syncthreads();

    for (int e = threadIdx.x; e < 64*32; e += 256) {
        int r = e >> 5, c4 = e & 31;
        float4 y = make_float4(0.f,0.f,0.f,0.f);
        int gr = row0 + r;
        if (gr < n) {
            float4 a4 = *(const float4*)&A[(base+gr)*CDIM + c4*4];
            int c = c4*4;
            y.x = fmaxf(fmaf(a4.x, s_sc[c+0], s_sf[c+0]), 0.f);
            y.y = fmaxf(fmaf(a4.y, s_sc[c+1], s_sf[c+1]), 0.f);
            y.z = fmaxf(fmaf(a4.z, s_sc[c+2], s_sf[c+2]), 0.f);
            y.w = fmaxf(fmaf(a4.w, s_sc[c+3], s_sf[c+3]), 0.f);
        }
        *(float4*)&s_h[r][c4*4] = y;
    }

    float acc[4][8];
    #pragma unroll
    for (int i = 0; i < 4; ++i)
        #pragma unroll
        for (int j = 0; j < 8; ++j) acc[i][j] = 0.f;
    int tx = threadIdx.x & 15, ty = threadIdx.x >> 4;
    int c0 = tx*8, r0 = ty*4;

    for (int kt = 0; kt < CDIM; kt += 32) {
        __syncthreads();
        for (int e = threadIdx.x; e < 32*32; e += 256) {
            int kr = e >> 5, c4 = e & 31;
            *(float4*)&s_w[kr][c4*4] = *(const float4*)&Wp[(kt+kr)*CDIM + c4*4];
        }
        __syncthreads();
        #pragma unroll
        for (int kk = 0; kk < 32; kk += 4) {
            float a[4][4];
            #pragma unroll
            for (int ri = 0; ri < 4; ++ri)
                *(float4*)a[ri] = *(const float4*)&s_h[r0+ri][kt+kk];
            #pragma unroll
            for (int dk = 0; dk < 4; ++dk) {
                float4 w0 = *(const float4*)&s_w[kk+dk][c0];
                float4 w1 = *(const float4*)&s_w[kk+dk][c0+4];
                #pragma unroll
                for (int ri = 0; ri < 4; ++ri) {
                    float av = a[ri][dk];
                    acc[ri][0]=fmaf(av,w0.x,acc[ri][0]); acc[ri][1]=fmaf(av,w0.y,acc[ri][1]);
                    acc[ri][2]=fmaf(av,w0.z,acc[ri][2]); acc[ri][3]=fmaf(av,w0.w,acc[ri][3]);
                    acc[ri][4]=fmaf(av,w1.x,acc[ri][4]); acc[ri][5]=fmaf(av,w1.y,acc[ri][5]);
                    acc[ri][6]=fmaf(av,w1.z,acc[ri][6]); acc[ri][7]=fmaf(av,w1.w,acc[ri][7]);
                }
            }
        }
    }

    #pragma unroll
    for (int ri = 0; ri < 4; ++ri) {
        int gr = row0 + r0 + ri;
        if (gr < n) {
            float* out = &Z[(base+gr)*CDIM + c0];
            #pragma unroll
            for (int j = 0; j < 8; ++j) out[j] = acc[ri][j] + bp[c0 + j];
        }
    }
}

// ---------------- K6: global BN stats ----------------
__global__ void k6_gstats(const float* __restrict__ Z, float* __restrict__ gstats)
{
    int row0 = blockIdx.x * 128;
    if (row0 >= NTOT) return;
    int nr = min(128, NTOT - row0);
    int c    = threadIdx.x & 127;
    int half = threadIdx.x >> 7;
    float s = 0.f, s2 = 0.f;
    for (int rr = half; rr < nr; rr += 2) {
        float a = Z[(row0+rr)*CDIM + c];
        s += a; s2 = fmaf(a, a, s2);
    }
    atomicAdd(&gstats[c], s);
    atomicAdd(&gstats[128 + c], s2);
}

// ---------------- K7: final BN + ReLU in place (float4) ----------------
__global__ void k7_final(float* __restrict__ Z, const float* __restrict__ gstats,
                         const float* __restrict__ gamma_p, const float* __restrict__ beta_p)
{
    __shared__ float s_sc[CDIM], s_sf[CDIM];
    if (threadIdx.x < CDIM) {
        int c = threadIdx.x;
        const float inv_n = 1.f / (float)NTOT;
        float mu  = gstats[c] * inv_n;
        float var = gstats[128 + c] * inv_n - mu*mu;
        float sc  = gamma_p[c] * rsqrtf(var + BNEPS);
        s_sc[c] = sc;
        s_sf[c] = beta_p[c] - mu*sc;
    }
    __syncthreads();
    int i4 = blockIdx.x * blockDim.x + threadIdx.x;
    if (i4 >= NTOT*32) return;
    float4 z = ((const float4*)Z)[i4];
    int c = (i4 & 31) * 4;
    z.x = fmaxf(fmaf(z.x, s_sc[c+0], s_sf[c+0]), 0.f);
    z.y = fmaxf(fmaf(z.y, s_sc[c+1], s_sf[c+1]), 0.f);
    z.z = fmaxf(fmaf(z.z, s_sc[c+2], s_sf[c+2]), 0.f);
    z.w = fmaxf(fmaf(z.w, s_sc[c+3], s_sf[c+3]), 0.f);
    ((float4*)Z)[i4] = z;
}

extern "C" void kernel_launch(void* const* d_in, const int* in_sizes, int n_in,
                              void* d_out, int out_size, void* d_ws, size_t ws_size,
                              hipStream_t stream)
{
    (void)in_sizes; (void)n_in; (void)out_size; (void)ws_size;
    const float* h_f  = (const float*)d_in[0];
    const float* x_f  = (const float*)d_in[1];
    const float* x_c  = (const float*)d_in[2];
    const float* h_c  = (const float*)d_in[3];
    const float* Wv   = (const float*)d_in[6];
    const float* Wo   = (const float*)d_in[7];
    const float* bo   = (const float*)d_in[8];
    const float* ga   = (const float*)d_in[9];
    const float* ba   = (const float*)d_in[10];
    const float* Wp   = (const float*)d_in[11];
    const float* bp   = (const float*)d_in[12];
    const float* gp   = (const float*)d_in[13];
    const float* betp = (const float*)d_in[14];

    char*  ws     = (char*)d_ws;
    float* W1     = (float*)ws;                        // 65536 B
    float* cstats = (float*)(ws + 65536);              // 19*256*4 = 19456 B
    float* gstats = (float*)(ws + 65536 + 19456);      // 1024 B
    int*   tidx   = (int*)(ws + 65536 + 20480);        // 50000*5*4 = 1,000,000 B
    float* A      = (float*)(ws + 65536 + 20480 + 1000000); // 25.6 MB
    float* Z      = (float*)d_out;

    hipMemsetAsync(ws + 65536, 0, 20480, stream);      // zero cstats + gstats

    k1_w1    <<<dim3(CDIM),        dim3(CDIM), 0, stream>>>(Wv, Wo, W1);
    k2_topk  <<<dim3(43, NCHUNKS), dim3(256),  0, stream>>>(x_c, h_c, tidx);
    k3_gemm1 <<<dim3(43, NCHUNKS), dim3(256),  0, stream>>>(x_f, h_f, tidx, W1, bo, A);
    k4_cstats<<<dim3(22, NCHUNKS), dim3(256),  0, stream>>>(A, cstats);
    k5_gemm2 <<<dim3(43, NCHUNKS), dim3(256),  0, stream>>>(A, Wp, bp, ga, ba, cstats, Z);
    k6_gstats<<<dim3(391),         dim3(256),  0, stream>>>(Z, gstats);
    k7_final <<<dim3((NTOT*32 + 255)/256), dim3(256), 0, stream>>>(Z, gstats, gp, betp);
}

// Round 8
// 266.790 us; speedup vs baseline: 1.9356x; 1.0519x over previous
//
#include <hip/hip_runtime.h>
#include <hip/hip_bf16.h>
#include <math.h>

#define NTOT    50000
#define CDIM    128
#define FCHUNK  2714
#define MCH     18
#define NREM    (NTOT - MCH*FCHUNK)   /* 1148 */
#define NCHUNKS 19
#define TOPKN   5
#define INNERD  512
#define BNEPS   1e-5f
#define SEGS    32
#define RPT     8
#define CAP     25

static __device__ __forceinline__ int chunk_n(int chunk) {
    return (chunk < MCH) ? FCHUNK : NREM;
}

// strict-> sorted insert == lax.top_k stable tie-break (ascending-j stream)
#define INS5(s, jj, V0,V1,V2,V3,V4,I0,I1,I2,I3,I4) \
    if (s > V4) { \
        if (s > V0)      { V4=V3;I4=I3; V3=V2;I3=I2; V2=V1;I2=I1; V1=V0;I1=I0; V0=s;I0=jj; } \
        else if (s > V1) { V4=V3;I4=I3; V3=V2;I3=I2; V2=V1;I2=I1; V1=s;I1=jj; } \
        else if (s > V2) { V4=V3;I4=I3; V3=V2;I3=I2; V2=s;I2=jj; } \
        else if (s > V3) { V4=V3;I4=I3; V3=s;I3=jj; } \
        else             { V4=s;I4=jj; } \
    }

// composite (val desc, idx asc) insert — order-independent == stable top-k
#define INS5C(s, jj, V0,V1,V2,V3,V4,I0,I1,I2,I3,I4) \
    if ((s > V4) || (s == V4 && jj < I4)) { \
        if ((s > V0) || (s == V0 && jj < I0))      { V4=V3;I4=I3; V3=V2;I3=I2; V2=V1;I2=I1; V1=V0;I1=I0; V0=s;I0=jj; } \
        else if ((s > V1) || (s == V1 && jj < I1)) { V4=V3;I4=I3; V3=V2;I3=I2; V2=V1;I2=I1; V1=s;I1=jj; } \
        else if ((s > V2) || (s == V2 && jj < I2)) { V4=V3;I4=I3; V3=V2;I3=I2; V2=s;I2=jj; } \
        else if ((s > V3) || (s == V3 && jj < I3)) { V4=V3;I4=I3; V3=s;I3=jj; } \
        else                                        { V4=s;I4=jj; } \
    }

#define CAS(x, y) { float lo_ = fminf(x, y), hi_ = fmaxf(x, y); x = lo_; y = hi_; }

// ---------------- K1: W1 = Wv @ Wo  (128x512 @ 512x128) ----------------
__global__ void k1_w1(const float* __restrict__ Wv, const float* __restrict__ Wo,
                      float* __restrict__ W1)
{
    __shared__ float s_wv[INNERD];
    int r = blockIdx.x;
    for (int t = threadIdx.x; t < INNERD; t += blockDim.x) s_wv[t] = Wv[r*INNERD + t];
    __syncthreads();
    int c = threadIdx.x;
    float acc = 0.f;
    #pragma unroll 8
    for (int k = 0; k < INNERD; ++k) acc = fmaf(s_wv[k], Wo[k*CDIM + c], acc);
    W1[r*CDIM + c] = acc;
}

// --- K2: per-chunk top-5: 8 rows/thread, 32 segs, threshold + append ---
__global__ __launch_bounds__(256) void k2_topk(const float* __restrict__ x_c,
                                               const float* __restrict__ h_c,
                                               int* __restrict__ tidx)
{
    __shared__ float s_xf[FCHUNK*3];          // 32568 B, packed float3
    __shared__ float scratch[3264];           // A: segmax[64][33]+thr | B: cnt/cv/cj
    int chunk = blockIdx.y;
    int base  = chunk * FCHUNK;
    int n     = chunk_n(chunk);
    int row0  = blockIdx.x * 64;
    if (row0 >= n) return;

    for (int e = threadIdx.x; e < n*3; e += 256) s_xf[e] = x_c[base*3 + e];
    __syncthreads();

    int seg = threadIdx.x & 31;
    int g   = threadIdx.x >> 5;               // 0..7; rows g, g+8, ..., g+56
    int seglen = ((n + SEGS - 1) / SEGS) | 1; // odd -> stride 3*odd coprime w/ 32
    int j0 = seg*seglen, j1 = min(n, j0 + seglen);

    float h0[RPT], h1[RPT], h2[RPT];
    #pragma unroll
    for (int r = 0; r < RPT; ++r) {
        int row = row0 + g + 8*r;
        bool v = row < n;
        h0[r] = v ? h_c[(base+row)*3  ] : 0.f;
        h1[r] = v ? h_c[(base+row)*3+1] : 0.f;
        h2[r] = v ? h_c[(base+row)*3+2] : 0.f;
    }

    // ---- pass 1: branchless segment maxes, 8 rows per x-read ----
    float m[RPT];
    #pragma unroll
    for (int r = 0; r < RPT; ++r) m[r] = -INFINITY;
    #pragma unroll 4
    for (int j = j0; j < j1; ++j) {
        float xx = s_xf[j*3], xy = s_xf[j*3+1], xz = s_xf[j*3+2];
        #pragma unroll
        for (int r = 0; r < RPT; ++r)
            m[r] = fmaxf(m[r], fmaf(xz,h2[r], fmaf(xy,h1[r], xx*h0[r])));
    }
    float* s_segmax = scratch;                // [64][33]
    float* s_thr    = scratch + 64*33;        // [64]
    #pragma unroll
    for (int r = 0; r < RPT; ++r) s_segmax[(g+8*r)*33 + seg] = m[r];
    __syncthreads();

    // ---- threshold: 5th largest of 8 supersegment maxes (T <= v5) ----
    if (threadIdx.x < 64) {
        int lr = threadIdx.x;
        float b0,b1,b2,b3,b4,b5,b6,b7;
        {
            const float* sm = &s_segmax[lr*33];
            b0 = fmaxf(fmaxf(sm[0],sm[1]),  fmaxf(sm[2],sm[3]));
            b1 = fmaxf(fmaxf(sm[4],sm[5]),  fmaxf(sm[6],sm[7]));
            b2 = fmaxf(fmaxf(sm[8],sm[9]),  fmaxf(sm[10],sm[11]));
            b3 = fmaxf(fmaxf(sm[12],sm[13]),fmaxf(sm[14],sm[15]));
            b4 = fmaxf(fmaxf(sm[16],sm[17]),fmaxf(sm[18],sm[19]));
            b5 = fmaxf(fmaxf(sm[20],sm[21]),fmaxf(sm[22],sm[23]));
            b6 = fmaxf(fmaxf(sm[24],sm[25]),fmaxf(sm[26],sm[27]));
            b7 = fmaxf(fmaxf(sm[28],sm[29]),fmaxf(sm[30],sm[31]));
        }
        CAS(b0,b1); CAS(b2,b3); CAS(b4,b5); CAS(b6,b7);
        CAS(b0,b2); CAS(b1,b3); CAS(b4,b6); CAS(b5,b7);
        CAS(b1,b2); CAS(b5,b6);
        CAS(b0,b4); CAS(b1,b5); CAS(b2,b6); CAS(b3,b7);
        CAS(b2,b4); CAS(b3,b5);
        CAS(b1,b2); CAS(b3,b4); CAS(b5,b6);
        s_thr[lr] = (row0 + lr < n) ? b3 : INFINITY;   // ascending[3] = 5th largest
    }
    __syncthreads();
    float thr[RPT];
    #pragma unroll
    for (int r = 0; r < RPT; ++r) thr[r] = s_thr[g + 8*r];
    __syncthreads();                          // thr in regs; scratch reusable

    // ---- overlay phase B: candidate buffers ----
    int*   s_cnt = (int*)scratch;             // [64]
    float* s_cv  = scratch + 64;              // [64][CAP]
    int*   s_cj  = (int*)(scratch + 64 + 64*CAP); // [64][CAP]
    if (threadIdx.x < 64) s_cnt[threadIdx.x] = 0;
    __syncthreads();

    // ---- pass 2: append candidates >= thr (identical fma order -> exact bits) ----
    #pragma unroll 4
    for (int j = j0; j < j1; ++j) {
        float xx = s_xf[j*3], xy = s_xf[j*3+1], xz = s_xf[j*3+2];
        #pragma unroll
        for (int r = 0; r < RPT; ++r) {
            float d = fmaf(xz,h2[r], fmaf(xy,h1[r], xx*h0[r]));
            if (!(d < thr[r])) {
                int lr = g + 8*r;
                int p = atomicAdd(&s_cnt[lr], 1);
                if (p < CAP) { s_cv[lr*CAP+p] = d; s_cj[lr*CAP+p] = j; }
            }
        }
    }
    __syncthreads();

    // ---- merge: composite top-5 over ~7 candidates per row ----
    if (threadIdx.x < 64) {
        int lr = threadIdx.x, row = row0 + lr;
        if (row < n) {
            float v0=-INFINITY,v1=-INFINITY,v2=-INFINITY,v3=-INFINITY,v4=-INFINITY;
            int i0=0x7fffffff,i1=0x7fffffff,i2=0x7fffffff,i3=0x7fffffff,i4=0x7fffffff;
            int mcnt = s_cnt[lr];
            if (mcnt <= CAP) {
                for (int t = 0; t < mcnt; ++t) {
                    float s = s_cv[lr*CAP + t]; int jj = s_cj[lr*CAP + t];
                    INS5C(s, jj, v0,v1,v2,v3,v4, i0,i1,i2,i3,i4);
                }
            } else {
                // overflow fallback (P ~ 2e-6/row): serial ascending-j rescan
                float ha = h_c[(base+row)*3], hb = h_c[(base+row)*3+1], hc2 = h_c[(base+row)*3+2];
                v0=v1=v2=v3=v4=-INFINITY; i0=i1=i2=i3=i4=0;
                for (int jj = 0; jj < n; ++jj) {
                    float s = fmaf(s_xf[jj*3+2],hc2, fmaf(s_xf[jj*3+1],hb, s_xf[jj*3]*ha));
                    INS5(s, jj, v0,v1,v2,v3,v4, i0,i1,i2,i3,i4);
                }
            }
            int o = (base+row)*TOPKN;
            tidx[o+0]=i0; tidx[o+1]=i1; tidx[o+2]=i2; tidx[o+3]=i3; tidx[o+4]=i4;
        }
    }
}

// ------- K3: scramble + gather + hsum, then A = hsum @ W1 + bo -------
__global__ __launch_bounds__(256) void k3_gemm1(const float* __restrict__ x_f,
                         const float* __restrict__ h_f,
                         const int* __restrict__ tidx, const float* __restrict__ W1,
                         const float* __restrict__ bo, float* __restrict__ A)
{
    __shared__ float s_h[64][132];
    __shared__ float s_w[32][128];
    __shared__ int   s_nb[64][TOPKN];
    int chunk = blockIdx.y;
    int base  = chunk * FCHUNK;
    int n     = chunk_n(chunk);
    int row0  = blockIdx.x * 64;
    if (row0 >= n) return;

    for (int e = threadIdx.x; e < 64*TOPKN; e += 256) {
        int r = e / TOPKN, k = e % TOPKN;
        int il = row0 + r;
        int nb = 0;
        if (il < n) {
            int p = il*TOPKN + k;             // faithful tidx.T flatten order
            int q, m;
            if (n == FCHUNK) { q = p / FCHUNK; m = p - q*FCHUNK; }
            else             { q = p / NREM;   m = p - q*NREM; }
            nb = tidx[(base + m)*TOPKN + q];
        }
        s_nb[r][k] = nb;
    }
    __syncthreads();

    for (int e = threadIdx.x; e < 64*32; e += 256) {
        int r = e >> 5, c4 = e & 31;
        float4 acc4 = make_float4(0.f,0.f,0.f,0.f);
        int gr = row0 + r;
        if (gr < n) {
            acc4 = *(const float4*)&x_f[(base+gr)*CDIM + c4*4];
            #pragma unroll
            for (int k = 0; k < TOPKN; ++k) {
                float4 h4 = *(const float4*)&h_f[(base + s_nb[r][k])*CDIM + c4*4];
                acc4.x += h4.x; acc4.y += h4.y; acc4.z += h4.z; acc4.w += h4.w;
            }
        }
        *(float4*)&s_h[r][c4*4] = acc4;
    }

    float acc[4][8];
    #pragma unroll
    for (int i = 0; i < 4; ++i)
        #pragma unroll
        for (int j = 0; j < 8; ++j) acc[i][j] = 0.f;
    int tx = threadIdx.x & 15, ty = threadIdx.x >> 4;
    int c0 = tx*8, r0 = ty*4;

    for (int kt = 0; kt < CDIM; kt += 32) {
        __syncthreads();
        for (int e = threadIdx.x; e < 32*32; e += 256) {
            int kr = e >> 5, c4 = e & 31;
            *(float4*)&s_w[kr][c4*4] = *(const float4*)&W1[(kt+kr)*CDIM + c4*4];
        }
        __syncthreads();
        #pragma unroll
        for (int kk = 0; kk < 32; kk += 4) {
            float a[4][4];
            #pragma unroll
            for (int ri = 0; ri < 4; ++ri)
                *(float4*)a[ri] = *(const float4*)&s_h[r0+ri][kt+kk];
            #pragma unroll
            for (int dk = 0; dk < 4; ++dk) {
                float4 w0 = *(const float4*)&s_w[kk+dk][c0];
                float4 w1 = *(const float4*)&s_w[kk+dk][c0+4];
                #pragma unroll
                for (int ri = 0; ri < 4; ++ri) {
                    float av = a[ri][dk];
                    acc[ri][0]=fmaf(av,w0.x,acc[ri][0]); acc[ri][1]=fmaf(av,w0.y,acc[ri][1]);
                    acc[ri][2]=fmaf(av,w0.z,acc[ri][2]); acc[ri][3]=fmaf(av,w0.w,acc[ri][3]);
                    acc[ri][4]=fmaf(av,w1.x,acc[ri][4]); acc[ri][5]=fmaf(av,w1.y,acc[ri][5]);
                    acc[ri][6]=fmaf(av,w1.z,acc[ri][6]); acc[ri][7]=fmaf(av,w1.w,acc[ri][7]);
                }
            }
        }
    }

    #pragma unroll
    for (int ri = 0; ri < 4; ++ri) {
        int gr = row0 + r0 + ri;
        if (gr < n) {
            float* out = &A[(base+gr)*CDIM + c0];
            #pragma unroll
            for (int j = 0; j < 8; ++j) out[j] = acc[ri][j] + bo[c0 + j];
        }
    }
}

// ---------------- K4: per-chunk BN stats (sum, sumsq) ----------------
__global__ void k4_cstats(const float* __restrict__ A, float* __restrict__ cstats)
{
    int chunk = blockIdx.y;
    int base  = chunk * FCHUNK;
    int n     = chunk_n(chunk);
    int row0  = blockIdx.x * 128;
    if (row0 >= n) return;
    int nr = min(128, n - row0);
    int c    = threadIdx.x & 127;
    int half = threadIdx.x >> 7;
    float s = 0.f, s2 = 0.f;
    for (int rr = half; rr < nr; rr += 2) {
        float a = A[(base+row0+rr)*CDIM + c];
        s += a; s2 = fmaf(a, a, s2);
    }
    atomicAdd(&cstats[chunk*256 + c], s);
    atomicAdd(&cstats[chunk*256 + 128 + c], s2);
}

// ------- K5: Y = relu(BN_chunk(A)); Z = Y @ Wp + bp  (fused) -------
__global__ __launch_bounds__(256) void k5_gemm2(const float* __restrict__ A,
                         const float* __restrict__ Wp,
                         const float* __restrict__ bp, const float* __restrict__ gamma_a,
                         const float* __restrict__ beta_a, const float* __restrict__ cstats,
                         float* __restrict__ Z)
{
    __shared__ float s_h[64][132];
    __shared__ float s_w[32][128];
    __shared__ float s_sc[CDIM], s_sf[CDIM];
    int chunk = blockIdx.y;
    int base  = chunk * FCHUNK;
    int n     = chunk_n(chunk);
    int row0  = blockIdx.x * 64;
    if (row0 >= n) return;

    if (threadIdx.x < CDIM) {
        int c = threadIdx.x;
        float inv_n = 1.f / (float)n;
        float mu  = cstats[chunk*256 + c] * inv_n;
        float var = cstats[chunk*256 + 128 + c] * inv_n - mu*mu;
        float sc  = gamma_a[c] * rsqrtf(var + BNEPS);
        s_sc[c] = sc;
        s_sf[c] = beta_a[c] - mu*sc;
    }
    __syncthreads();

    for (int e = threadIdx.x; e < 64*32; e += 256) {
        int r = e >> 5, c4 = e & 31;
        float4 y = make_float4(0.f,0.f,0.f,0.f);
        int gr = row0 + r;
        if (gr < n) {
            float4 a4 = *(const float4*)&A[(base+gr)*CDIM + c4*4];
            int c = c4*4;
            y.x = fmaxf(fmaf(a4.x, s_sc[c+0], s_sf[c+0]), 0.f);
            y.y = fmaxf(fmaf(a4.y, s_sc[c+1], s_sf[c+1]), 0.f);
            y.z = fmaxf(fmaf(a4.z, s_sc[c+2], s_sf[c+2]), 0.f);
            y.w = fmaxf(fmaf(a4.w, s_sc[c+3], s_sf[c+3]), 0.f);
        }
        *(float4*)&s_h[r][c4*4] = y;
    }

    float acc[4][8];
    #pragma unroll
    for (int i = 0; i < 4; ++i)
        #pragma unroll
        for (int j = 0; j < 8; ++j) acc[i][j] = 0.f;
    int tx = threadIdx.x & 15, ty = threadIdx.x >> 4;
    int c0 = tx*8, r0 = ty*4;

    for (int kt = 0; kt < CDIM; kt += 32) {
        __syncthreads();
        for (int e = threadIdx.x; e < 32*32; e += 256) {
            int kr = e >> 5, c4 = e & 31;
            *(float4*)&s_w[kr][c4*4] = *(const float4*)&Wp[(kt+kr)*CDIM + c4*4];
        }
        __syncthreads();
        #pragma unroll
        for (int kk = 0; kk < 32; kk += 4) {
            float a[4][4];
            #pragma unroll
            for (int ri = 0; ri < 4; ++ri)
                *(float4*)a[ri] = *(const float4*)&s_h[r0+ri][kt+kk];
            #pragma unroll
            for (int dk = 0; dk < 4; ++dk) {
                float4 w0 = *(const float4*)&s_w[kk+dk][c0];
                float4 w1 = *(const float4*)&s_w[kk+dk][c0+4];
                #pragma unroll
                for (int ri = 0; ri < 4; ++ri) {
                    float av = a[ri][dk];
                    acc[ri][0]=fmaf(av,w0.x,acc[ri][0]); acc[ri][1]=fmaf(av,w0.y,acc[ri][1]);
                    acc[ri][2]=fmaf(av,w0.z,acc[ri][2]); acc[ri][3]=fmaf(av,w0.w,acc[ri][3]);
                    acc[ri][4]=fmaf(av,w1.x,acc[ri][4]); acc[ri][5]=fmaf(av,w1.y,acc[ri][5]);
                    acc[ri][6]=fmaf(av,w1.z,acc[ri][6]); acc[ri][7]=fmaf(av,w1.w,acc[ri][7]);
                }
            }
        }
    }

    #pragma unroll
    for (int ri = 0; ri < 4; ++ri) {
        int gr = row0 + r0 + ri;
        if (gr < n) {
            float* out = &Z[(base+gr)*CDIM + c0];
            #pragma unroll
            for (int j = 0; j < 8; ++j) out[j] = acc[ri][j] + bp[c0 + j];
        }
    }
}

// ---------------- K6: global BN stats ----------------
__global__ void k6_gstats(const float* __restrict__ Z, float* __restrict__ gstats)
{
    int row0 = blockIdx.x * 128;
    if (row0 >= NTOT) return;
    int nr = min(128, NTOT - row0);
    int c    = threadIdx.x & 127;
    int half = threadIdx.x >> 7;
    float s = 0.f, s2 = 0.f;
    for (int rr = half; rr < nr; rr += 2) {
        float a = Z[(row0+rr)*CDIM + c];
        s += a; s2 = fmaf(a, a, s2);
    }
    atomicAdd(&gstats[c], s);
    atomicAdd(&gstats[128 + c], s2);
}

// ---------------- K7: final BN + ReLU in place (float4) ----------------
__global__ void k7_final(float* __restrict__ Z, const float* __restrict__ gstats,
                         const float* __restrict__ gamma_p, const float* __restrict__ beta_p)
{
    __shared__ float s_sc[CDIM], s_sf[CDIM];
    if (threadIdx.x < CDIM) {
        int c = threadIdx.x;
        const float inv_n = 1.f / (float)NTOT;
        float mu  = gstats[c] * inv_n;
        float var = gstats[128 + c] * inv_n - mu*mu;
        float sc  = gamma_p[c] * rsqrtf(var + BNEPS);
        s_sc[c] = sc;
        s_sf[c] = beta_p[c] - mu*sc;
    }
    __syncthreads();
    int i4 = blockIdx.x * blockDim.x + threadIdx.x;
    if (i4 >= NTOT*32) return;
    float4 z = ((const float4*)Z)[i4];
    int c = (i4 & 31) * 4;
    z.x = fmaxf(fmaf(z.x, s_sc[c+0], s_sf[c+0]), 0.f);
    z.y = fmaxf(fmaf(z.y, s_sc[c+1], s_sf[c+1]), 0.f);
    z.z = fmaxf(fmaf(z.z, s_sc[c+2], s_sf[c+2]), 0.f);
    z.w = fmaxf(fmaf(z.w, s_sc[c+3], s_sf[c+3]), 0.f);
    ((float4*)Z)[i4] = z;
}

extern "C" void kernel_launch(void* const* d_in, const int* in_sizes, int n_in,
                              void* d_out, int out_size, void* d_ws, size_t ws_size,
                              hipStream_t stream)
{
    (void)in_sizes; (void)n_in; (void)out_size; (void)ws_size;
    const float* h_f  = (const float*)d_in[0];
    const float* x_f  = (const float*)d_in[1];
    const float* x_c  = (const float*)d_in[2];
    const float* h_c  = (const float*)d_in[3];
    const float* Wv   = (const float*)d_in[6];
    const float* Wo   = (const float*)d_in[7];
    const float* bo   = (const float*)d_in[8];
    const float* ga   = (const float*)d_in[9];
    const float* ba   = (const float*)d_in[10];
    const float* Wp   = (const float*)d_in[11];
    const float* bp   = (const float*)d_in[12];
    const float* gp   = (const float*)d_in[13];
    const float* betp = (const float*)d_in[14];

    char*  ws     = (char*)d_ws;
    float* W1     = (float*)ws;                        // 65536 B
    float* cstats = (float*)(ws + 65536);              // 19*256*4 = 19456 B
    float* gstats = (float*)(ws + 65536 + 19456);      // 1024 B
    int*   tidx   = (int*)(ws + 65536 + 20480);        // 50000*5*4 = 1,000,000 B
    float* A      = (float*)(ws + 65536 + 20480 + 1000000); // 25.6 MB
    float* Z      = (float*)d_out;

    hipMemsetAsync(ws + 65536, 0, 20480, stream);      // zero cstats + gstats

    k1_w1    <<<dim3(CDIM),        dim3(CDIM), 0, stream>>>(Wv, Wo, W1);
    k2_topk  <<<dim3(43, NCHUNKS), dim3(256),  0, stream>>>(x_c, h_c, tidx);
    k3_gemm1 <<<dim3(43, NCHUNKS), dim3(256),  0, stream>>>(x_f, h_f, tidx, W1, bo, A);
    k4_cstats<<<dim3(22, NCHUNKS), dim3(256),  0, stream>>>(A, cstats);
    k5_gemm2 <<<dim3(43, NCHUNKS), dim3(256),  0, stream>>>(A, Wp, bp, ga, ba, cstats, Z);
    k6_gstats<<<dim3(391),         dim3(256),  0, stream>>>(Z, gstats);
    k7_final <<<dim3((NTOT*32 + 255)/256), dim3(256), 0, stream>>>(Z, gstats, gp, betp);
}